// Round 5
// baseline (1801.156 us; speedup 1.0000x reference)
//
#include <hip/hip_runtime.h>
#include <hip/hip_bf16.h>

typedef unsigned short u16;
typedef unsigned int u32;
typedef __attribute__((ext_vector_type(2))) unsigned int u32x2;
typedef __attribute__((ext_vector_type(4))) float f32x4;
typedef __attribute__((ext_vector_type(8))) __bf16 bf16x8;
typedef __attribute__((ext_vector_type(8))) short s16x8;

#define DEVI static __device__ __forceinline__

// ---------- scalar helpers ----------
DEVI u16 f2bf(float x) {
  union { float f; u32 u; } v; v.f = x;
  u32 r = v.u + 0x7fffu + ((v.u >> 16) & 1u);
  return (u16)(r >> 16);
}
DEVI float bf2f(u16 h) { union { u32 u; float f; } v; v.u = ((u32)h) << 16; return v.f; }
DEVI u32 pk2bf(float a, float b) { return (u32)f2bf(a) | ((u32)f2bf(b) << 16); }
DEVI float sigm(float x) { return 1.f / (1.f + __expf(-x)); }
DEVI float tanh_(float x) {
  float a = fabsf(x);
  float e = __expf(-2.f * a);
  float t = (1.f - e) / (1.f + e);
  return copysignf(t, x);
}

DEVI void gl_lds16(const u16* g, void* l) {
  __builtin_amdgcn_global_load_lds(
      (const __attribute__((address_space(1))) u32*)(const void*)g,
      (__attribute__((address_space(3))) u32*)l, 16, 0, 0);
}
DEVI f32x4 mfma16(bf16x8 a, bf16x8 b, f32x4 c) {
  return __builtin_amdgcn_mfma_f32_16x16x32_bf16(a, b, c, 0, 0, 0);
}

// ---------- prep kernels ----------
__global__ void sums_k(const float* __restrict__ adj, float* __restrict__ rs, float* __restrict__ cs) {
  __shared__ float red[256];
  int bid = blockIdx.x, tid = threadIdx.x;
  if (bid < 1024) {
    float a = 0.f;
    for (int j = tid; j < 1024; j += 256) a += adj[bid * 1024 + j];
    red[tid] = a; __syncthreads();
    for (int s = 128; s; s >>= 1) { if (tid < s) red[tid] += red[tid + s]; __syncthreads(); }
    if (!tid) rs[bid] = red[0];
  } else {
    int c0 = (bid - 1024) * 64;
    int c = tid & 63, r0 = tid >> 6;
    float a = 0.f;
    for (int r = r0; r < 1024; r += 4) a += adj[r * 1024 + c0 + c];
    red[tid] = a; __syncthreads();
    if (tid < 64) cs[c0 + c] = red[c] + red[64 + c] + red[128 + c] + red[192 + c];
  }
}

__global__ void s0_build(const float* __restrict__ adj, const float* __restrict__ rs, u16* __restrict__ S0) {
  __shared__ float tile[32][33];
  int i0 = blockIdx.x * 32, j0 = blockIdx.y * 32;
  int tx = threadIdx.x & 31, ty = threadIdx.x >> 5;
  for (int yy = ty; yy < 32; yy += 8)
    tile[yy][tx] = adj[(j0 + yy) * 1024 + i0 + tx];
  __syncthreads();
  for (int yy = ty; yy < 32; yy += 8)
    S0[(i0 + yy) * 1024 + j0 + tx] = f2bf(tile[tx][yy] / rs[j0 + tx]);
}

__global__ void s1_build(const float* __restrict__ adj, const float* __restrict__ cs, u16* __restrict__ S1) {
  int idx = blockIdx.x * 256 + threadIdx.x;
  int j = idx & 1023;
  S1[idx] = f2bf(adj[idx] / cs[j]);
}

// pack h-part weights with cheb-elimination fold; pure full segments.
__global__ void pack_w(const float* __restrict__ src, u16* __restrict__ dst,
                       int NO, int Ktot, int off0, int off1) {
  int idx = blockIdx.x * 256 + threadIdx.x;
  if (idx >= NO * Ktot) return;
  int o = idx / Ktot, k = idx % Ktot;
  int seg = k >> 7, i = k & 127;
  int mo = seg % 6;
  int pos = ((seg / 6) ? off1 : off0) + i;
  const float* wr = src + (long)pos * 5 * NO + o;
  float v;
  switch (mo) {
    case 0: case 1: v = wr[0] - wr[(long)2 * NO] - wr[(long)4 * NO]; break;
    case 2: v = wr[(long)1 * NO]; break;
    case 3: v = 2.f * wr[(long)2 * NO]; break;
    case 4: v = wr[(long)3 * NO]; break;
    default: v = 2.f * wr[(long)4 * NO]; break;
  }
  dst[idx] = f2bf(v);
}

// h (B, N*128) fp32 -> chain hi/lo (N, B*128) bf16
__global__ void build_hx(const float* __restrict__ src, u16* __restrict__ hi, u16* __restrict__ lo) {
  long idx = (long)blockIdx.x * 256 + threadIdx.x;
  int u = (int)(idx & 127); long row = idx >> 7;
  int b = (int)(row >> 10), n = (int)(row & 1023);
  float v = src[idx];
  u16 h = f2bf(v);
  long d = (long)n * 8192 + b * 128 + u;
  hi[d] = h;
  lo[d] = f2bf(v - bf2f(h));
}

// ---------- x-part (layer 0): exact fp32 path ----------
__global__ void xch0_build(const float* __restrict__ inp, float* __restrict__ x0) {
  int idx = blockIdx.x * 256 + threadIdx.x;   // 131072
  int n = idx >> 7, c = idx & 127, b = c >> 1, d = c & 1;
  x0[idx] = inp[b * 2048 + n * 2 + d];
}

__global__ void xch_diffuse(const u16* __restrict__ S, const float* __restrict__ xin,
                            float* __restrict__ xout) {
  int n = blockIdx.x, c = threadIdx.x;
  float acc = 0.f;
  for (int k = 0; k < 1024; k++) acc += bf2f(S[n * 1024 + k]) * xin[k * 128 + c];
  xout[n * 128 + c] = acc;
}

__global__ void xch_cheb(const u16* __restrict__ S, const float* __restrict__ xin,
                         const float* __restrict__ x0, float* __restrict__ xout) {
  int n = blockIdx.x, c = threadIdx.x;
  float acc = 0.f;
  for (int k = 0; k < 1024; k++) acc += bf2f(S[n * 1024 + k]) * xin[k * 128 + c];
  xout[n * 128 + c] = 2.f * acc - x0[n * 128 + c];
}

__global__ void xg_build(const float* __restrict__ gw0, const float* __restrict__ cw0,
                         const float* __restrict__ xch,
                         u16* __restrict__ xgg, u16* __restrict__ xgc) {
  int r = blockIdx.x;           // 65536
  int n = r >> 6, b = r & 63;
  int t = threadIdx.x;          // 256
  __shared__ float xv[10];
  if (t < 10) { int m = t % 5, p = t / 5; xv[t] = xch[(long)m * 131072 + n * 128 + b * 2 + p]; }
  __syncthreads();
  float a = 0.f;
#pragma unroll
  for (int q = 0; q < 10; q++) { int m = q % 5, p = q / 5;
    a += gw0[(long)(p * 5 + m) * 256 + t] * xv[q]; }
  xgg[(long)r * 256 + t] = f2bf(a);
  if (t < 128) {
    float a2 = 0.f;
#pragma unroll
    for (int q = 0; q < 10; q++) { int m = q % 5, p = q / 5;
      a2 += cw0[(long)(p * 5 + m) * 128 + t] * xv[q]; }
    xgc[(long)r * 128 + t] = f2bf(a2);
  }
}

// ---------- diffusion GEMM:  Y[n][f] = sum_k S[n][k] * X[k][f]  (F = 8192) ----------
// A-operand (X^T tile) via reg-staged LDS transpose (plain-correct), B = S rows.
__global__ __launch_bounds__(256) void gemm_diff(
    const u16* __restrict__ X, const u16* __restrict__ S, u16* __restrict__ Y)
{
  __shared__ char smem[32768];
  const int tid = threadIdx.x;
  const int wid = tid >> 6, lane = tid & 63;
  const int wr = wid >> 1, wc = wid & 1;
  const int l15 = lane & 15, l4 = lane >> 4;
  const int ftile = blockIdx.x * 128;
  const int ntile = blockIdx.y * 128;

  char* A0 = smem;          char* A1 = smem + 8192;
  char* B0 = smem + 16384;  char* B1 = smem + 24576;

  const int b_row = lane >> 2, b_kcp = lane & 3;

  f32x4 acc[4][4];
#pragma unroll
  for (int i = 0; i < 4; i++)
#pragma unroll
    for (int j = 0; j < 4; j++) acc[i][j] = (f32x4){0.f, 0.f, 0.f, 0.f};

  auto stage = [&](char* Ab, char* Bb, int ks) {
    const int k0 = ks * 32;
    // B tile: S rows, async LDS, XOR-chunk swizzle (same pattern as gemm_wseg)
#pragma unroll
    for (int c = 0; c < 2; c++) {
      const int cc = wid * 2 + c;
      const int row = cc * 16 + b_row;
      gl_lds16(S + (long)(ntile + row) * 1024 + k0 + ((b_kcp ^ (row & 3)) * 8), Bb + cc * 1024);
    }
    // A tile: X[k0..k0+31][ftile..ftile+127] transposed into LDS [f][k] (64B rows),
    // chunk position (kc ^ (f&3)) holds k-chunk kc.
    u16* Ap = (u16*)Ab;
#pragma unroll
    for (int c = 0; c < 2; c++) {
      const int q = tid * 2 + c;        // [0,512) : 8-elem chunks
      const int k = q >> 4;             // [0,32)
      const int f8 = q & 15;            // [0,16)
      s16x8 v = *(const s16x8*)(X + (long)(k0 + k) * 8192 + ftile + f8 * 8);
      const int kc = k >> 3, kl = k & 7;
#pragma unroll
      for (int e = 0; e < 8; e++) {
        const int f = f8 * 8 + e;
        Ap[f * 32 + ((kc ^ (f & 3)) << 3) + kl] = (u16)v[e];
      }
    }
  };

  stage(A0, B0, 0);
  __syncthreads();

  char* cA = A0; char* cB = B0; char* nA = A1; char* nB = B1;
  for (int ks = 0; ks < 32; ks++) {
    if (ks < 31) stage(nA, nB, ks + 1);
    bf16x8 af[4], bfr[4];
#pragma unroll
    for (int mb = 0; mb < 4; mb++) {
      const int row = wr * 64 + mb * 16 + l15;
      af[mb] = *(const bf16x8*)(cA + row * 64 + ((l4 ^ (row & 3)) * 16));
    }
#pragma unroll
    for (int nb = 0; nb < 4; nb++) {
      const int row = wc * 64 + nb * 16 + l15;
      bfr[nb] = *(const bf16x8*)(cB + row * 64 + ((l4 ^ (row & 3)) * 16));
    }
#pragma unroll
    for (int mb = 0; mb < 4; mb++)
#pragma unroll
      for (int nb = 0; nb < 4; nb++)
        acc[mb][nb] = mfma16(af[mb], bfr[nb], acc[mb][nb]);
    __syncthreads();
    { char* t = cA; cA = nA; nA = t; t = cB; cB = nB; nB = t; }
  }

#pragma unroll
  for (int mb = 0; mb < 4; mb++) {
#pragma unroll
    for (int nb = 0; nb < 4; nb++) {
      const int f = ftile + wr * 64 + mb * 16 + l4 * 4;
      const int n = ntile + wc * 64 + nb * 16 + l15;
      const long off = (long)n * 8192 + f;
      f32x4 v = acc[mb][nb];
      u32x2 wv; wv[0] = pk2bf(v[0], v[1]); wv[1] = pk2bf(v[2], v[3]);
      *(u32x2*)(Y + off) = wv;
    }
  }
}

// ---------- W GEMM with fused epilogue; pure full segments ----------
struct Segs { const u16* p[12]; };
DEVI const u16* seg_sel(const Segs& s, int i) {
  switch (i) {
    case 0: return s.p[0]; case 1: return s.p[1]; case 2: return s.p[2];
    case 3: return s.p[3]; case 4: return s.p[4]; case 5: return s.p[5];
    case 6: return s.p[6]; case 7: return s.p[7]; case 8: return s.p[8];
    case 9: return s.p[9]; case 10: return s.p[10]; default: return s.p[11];
  }
}

template<int EPI>   // 0 = GATE (sigmoid -> r*h split + u bf16), 1 = CAND (tanh -> hnew)
__global__ __launch_bounds__(256) void gemm_wseg(
    Segs segs, const u16* __restrict__ WT, int Ktot,
    const float* __restrict__ bias, const float* __restrict__ Hprev,
    const u16* __restrict__ xadd,
    u16* __restrict__ rh_hi, u16* __restrict__ rh_lo, u16* __restrict__ usig,
    float* __restrict__ hnew_out, u16* __restrict__ xa_hi, u16* __restrict__ xa_lo)
{
  __shared__ char smem[32768];
  const int tid = threadIdx.x, wid = tid >> 6, lane = tid & 63;
  const int wr = wid >> 1, wc = wid & 1, l15 = lane & 15, l4 = lane >> 4;
  const int otile = blockIdx.x * 128, rtile = blockIdx.y * 128;
  char* A0 = smem;          char* A1 = smem + 8192;
  char* B0 = smem + 16384;  char* B1 = smem + 24576;
  const int s_row = lane >> 2, s_kcp = lane & 3;

  f32x4 acc[4][4];
#pragma unroll
  for (int i = 0; i < 4; i++)
#pragma unroll
    for (int j = 0; j < 4; j++) acc[i][j] = (f32x4){0.f, 0.f, 0.f, 0.f};

  const int NKS = Ktot >> 5;
  auto stage = [&](char* Ab, char* Bb, int ks) {
    const int k0 = ks * 32;
    const int sidx = ks >> 2, si0 = (ks & 3) * 32;
    const u16* sp = seg_sel(segs, sidx);
#pragma unroll
    for (int c = 0; c < 2; c++) {
      const int bb = wid * 2 + c;
      const int arow = bb * 16 + s_row;
      gl_lds16(WT + (long)(otile + arow) * Ktot + k0 + ((s_kcp ^ (arow & 3)) * 8), Ab + bb * 1024);
      const int r = rtile + bb * 16 + s_row;
      gl_lds16(sp + (long)(r >> 6) * 8192 + (r & 63) * 128 + si0 + ((s_kcp ^ (r & 3)) * 8), Bb + bb * 1024);
    }
  };

  stage(A0, B0, 0);
  __syncthreads();
  char* cA = A0; char* cB = B0; char* nA = A1; char* nB = B1;
  for (int ks = 0; ks < NKS; ks++) {
    if (ks + 1 < NKS) stage(nA, nB, ks + 1);
    bf16x8 af[4], bfr[4];
#pragma unroll
    for (int mb = 0; mb < 4; mb++) {
      const int row = wr * 64 + mb * 16 + l15;
      af[mb] = *(const bf16x8*)(cA + row * 64 + ((l4 ^ (row & 3)) * 16));
    }
#pragma unroll
    for (int nb = 0; nb < 4; nb++) {
      const int row = wc * 64 + nb * 16 + l15;
      bfr[nb] = *(const bf16x8*)(cB + row * 64 + ((l4 ^ (row & 3)) * 16));
    }
#pragma unroll
    for (int mb = 0; mb < 4; mb++)
#pragma unroll
      for (int nb = 0; nb < 4; nb++)
        acc[mb][nb] = mfma16(af[mb], bfr[nb], acc[mb][nb]);
    __syncthreads();
    { char* t = cA; cA = nA; nA = t; t = cB; cB = nB; nB = t; }
  }

#pragma unroll
  for (int mb = 0; mb < 4; mb++) {
#pragma unroll
    for (int nb = 0; nb < 4; nb++) {
      const int o = otile + wr * 64 + mb * 16 + l4 * 4;
      const int rr = rtile + wc * 64 + nb * 16 + l15;
      const int n = rr >> 6, b = rr & 63;
      f32x4 v = acc[mb][nb];
      float4 bv = *(const float4*)(bias + o);
      float a0 = 0.f, a1 = 0.f, a2 = 0.f, a3 = 0.f;
      if (xadd != nullptr) {
        const int xs = (EPI == 0) ? 256 : 128;
        u32x2 xv = *(const u32x2*)(xadd + (long)rr * xs + o);
        a0 = bf2f((u16)(xv[0] & 0xffffu)); a1 = bf2f((u16)(xv[0] >> 16));
        a2 = bf2f((u16)(xv[1] & 0xffffu)); a3 = bf2f((u16)(xv[1] >> 16));
      }
      if (EPI == 0) {
        float s0 = sigm(v[0] + bv.x + a0), s1 = sigm(v[1] + bv.y + a1);
        float s2 = sigm(v[2] + bv.z + a2), s3 = sigm(v[3] + bv.w + a3);
        if (o < 128) {
          float4 hv = *(const float4*)(Hprev + (long)b * 131072 + n * 128 + o);
          float r0 = s0 * hv.x, r1 = s1 * hv.y, r2 = s2 * hv.z, r3 = s3 * hv.w;
          u16 h0 = f2bf(r0), h1 = f2bf(r1), h2 = f2bf(r2), h3 = f2bf(r3);
          long d = (long)n * 8192 + b * 128 + o;
          u32x2 wh; wh[0] = (u32)h0 | ((u32)h1 << 16); wh[1] = (u32)h2 | ((u32)h3 << 16);
          *(u32x2*)(rh_hi + d) = wh;
          u32x2 wl; wl[0] = pk2bf(r0 - bf2f(h0), r1 - bf2f(h1));
          wl[1] = pk2bf(r2 - bf2f(h2), r3 - bf2f(h3));
          *(u32x2*)(rh_lo + d) = wl;
        } else {
          u32x2 wu; wu[0] = pk2bf(s0, s1); wu[1] = pk2bf(s2, s3);
          *(u32x2*)(usig + (long)rr * 128 + (o - 128)) = wu;
        }
      } else {
        float c0 = tanh_(v[0] + bv.x + a0), c1 = tanh_(v[1] + bv.y + a1);
        float c2 = tanh_(v[2] + bv.z + a2), c3 = tanh_(v[3] + bv.w + a3);
        u32x2 uv = *(const u32x2*)(usig + (long)rr * 128 + o);
        float u0 = bf2f((u16)(uv[0] & 0xffffu)), u1 = bf2f((u16)(uv[0] >> 16));
        float u2 = bf2f((u16)(uv[1] & 0xffffu)), u3 = bf2f((u16)(uv[1] >> 16));
        float4 hv = *(const float4*)(Hprev + (long)b * 131072 + n * 128 + o);
        float h0n = u0 * hv.x + (1.f - u0) * c0;
        float h1n = u1 * hv.y + (1.f - u1) * c1;
        float h2n = u2 * hv.z + (1.f - u2) * c2;
        float h3n = u3 * hv.w + (1.f - u3) * c3;
        *(float4*)(hnew_out + (long)b * 131072 + n * 128 + o) = make_float4(h0n, h1n, h2n, h3n);
        if (xa_hi != nullptr) {
          u16 x0 = f2bf(h0n), x1 = f2bf(h1n), x2 = f2bf(h2n), x3 = f2bf(h3n);
          long d = (long)n * 8192 + b * 128 + o;
          u32x2 wh; wh[0] = (u32)x0 | ((u32)x1 << 16); wh[1] = (u32)x2 | ((u32)x3 << 16);
          *(u32x2*)(xa_hi + d) = wh;
          u32x2 wl; wl[0] = pk2bf(h0n - bf2f(x0), h1n - bf2f(x1));
          wl[1] = pk2bf(h2n - bf2f(x2), h3n - bf2f(x3));
          *(u32x2*)(xa_lo + d) = wl;
        }
      }
    }
  }
}

// ---------- projection ----------
__global__ __launch_bounds__(256) void proj_k(const float* __restrict__ h1n, const float* __restrict__ pw,
                                              const float* __restrict__ pb, float* __restrict__ out) {
  int wid = threadIdx.x >> 6, lane = threadIdx.x & 63;
  int r = blockIdx.x * 4 + wid;
  int b = r >> 10, n = r & 1023;
  const float* hp = h1n + (long)b * 131072 + n * 128;
  float ha = hp[lane], hb = hp[lane + 64];
  float p0 = ha * pw[lane * 2]     + hb * pw[(lane + 64) * 2];
  float p1 = ha * pw[lane * 2 + 1] + hb * pw[(lane + 64) * 2 + 1];
  for (int off = 32; off; off >>= 1) { p0 += __shfl_down(p0, off); p1 += __shfl_down(p1, off); }
  if (!lane) {
    out[(long)b * 2048 + n * 2]     = p0 + pb[0];
    out[(long)b * 2048 + n * 2 + 1] = p1 + pb[1];
  }
}

// ---------- host ----------
extern "C" void kernel_launch(void* const* d_in, const int* in_sizes, int n_in,
                              void* d_out, int out_size, void* d_ws, size_t ws_size,
                              hipStream_t stream) {
  (void)in_sizes; (void)n_in; (void)out_size; (void)ws_size;
  const float* inputs = (const float*)d_in[0];
  const float* hidden = (const float*)d_in[1];
  const float* adj    = (const float*)d_in[2];
  const float* gw0 = (const float*)d_in[3];
  const float* gb0 = (const float*)d_in[4];
  const float* cw0 = (const float*)d_in[5];
  const float* cb0 = (const float*)d_in[6];
  const float* gw1 = (const float*)d_in[7];
  const float* gb1 = (const float*)d_in[8];
  const float* cw1 = (const float*)d_in[9];
  const float* cb1 = (const float*)d_in[10];
  const float* pw  = (const float*)d_in[11];
  const float* pb  = (const float*)d_in[12];

  float* out    = (float*)d_out;
  float* out_h0 = out + 131072;
  float* out_h1 = out_h0 + 8388608;
  const float* h0 = hidden;
  const float* h1 = hidden + 8388608;

  // h1 hi/lo chains live in the (not-yet-written) out_h1 region of d_out.
  u16* OH1a = (u16*)out_h1;
  u16* OH1b = OH1a + 8388608;

  char* wp = (char*)d_ws;
  auto alloc = [&](size_t bytes) { char* r = wp; wp += (bytes + 255) & ~(size_t)255; return r; };
  u16*   S0b  = (u16*)  alloc(1048576 * 2);
  u16*   S1b  = (u16*)  alloc(1048576 * 2);
  float* rs   = (float*)alloc(1024 * 4);
  float* cs   = (float*)alloc(1024 * 4);
  u16*   WG0  = (u16*)  alloc((size_t)256 * 768 * 2);
  u16*   WC0  = (u16*)  alloc((size_t)128 * 768 * 2);
  u16*   WG1  = (u16*)  alloc((size_t)256 * 1536 * 2);
  u16*   WC1  = (u16*)  alloc((size_t)128 * 1536 * 2);
  u16*   Bb   = (u16*)  alloc((size_t)9 * 8388608 * 2);    // 9 chain buffers
  u16*   USIG = (u16*)  alloc((size_t)8388608 * 2);
  float* XCH  = (float*)alloc((size_t)5 * 131072 * 4);     // fp32 x-chains T0..T4
  u16*   XGB  = (u16*)  alloc((size_t)3 * 8388608 * 2);    // XG block (3 chain-slots)
  auto BB = [&](int i) { return Bb + (size_t)i * 8388608; };
  auto XS = [&](int i) { return XGB + (size_t)i * 8388608; };
  auto XC = [&](int i) { return XCH + (size_t)i * 131072; };
  u16* XGg = XGB;                 // 65536 x 256 bf16 (spans XS0+XS1)
  u16* XGc = XGB + 16777216;      // 65536 x 128 bf16 (XS2)

  // prep
  sums_k<<<1040, 256, 0, stream>>>(adj, rs, cs);
  s0_build<<<dim3(32, 32), 256, 0, stream>>>(adj, rs, S0b);
  s1_build<<<4096, 256, 0, stream>>>(adj, cs, S1b);
  pack_w<<<768,  256, 0, stream>>>(gw0, WG0, 256, 768, 2, 0);
  pack_w<<<384,  256, 0, stream>>>(cw0, WC0, 128, 768, 2, 0);
  pack_w<<<1536, 256, 0, stream>>>(gw1, WG1, 256, 1536, 0, 128);
  pack_w<<<768,  256, 0, stream>>>(cw1, WC1, 128, 1536, 0, 128);
  build_hx<<<32768, 256, 0, stream>>>(h0, BB(0), BB(1));
  build_hx<<<32768, 256, 0, stream>>>(h1, OH1a, OH1b);

  // x-part: exact chains + additive preacts
  xch0_build<<<512, 256, 0, stream>>>(inputs, XC(0));
  xch_diffuse<<<1024, 128, 0, stream>>>(S0b, XC(0), XC(1));
  xch_cheb   <<<1024, 128, 0, stream>>>(S0b, XC(1), XC(0), XC(2));
  xch_diffuse<<<1024, 128, 0, stream>>>(S1b, XC(0), XC(3));
  xch_cheb   <<<1024, 128, 0, stream>>>(S1b, XC(3), XC(0), XC(4));
  xg_build<<<65536, 256, 0, stream>>>(gw0, cw0, XCH, XGg, XGc);

  // layer 0 gate s-chains: s1=S0x, s2=S0s1, s3=S1x, s4=S1s3
  gemm_diff<<<dim3(64, 8), 256, 0, stream>>>(BB(0), S0b, BB(2));
  gemm_diff<<<dim3(64, 8), 256, 0, stream>>>(BB(2), S0b, BB(3));
  gemm_diff<<<dim3(64, 8), 256, 0, stream>>>(BB(0), S1b, BB(4));
  gemm_diff<<<dim3(64, 8), 256, 0, stream>>>(BB(4), S1b, BB(5));

  // GATE0: rh -> BB6/BB7, u -> USIG
  Segs sg0{};
  sg0.p[0] = BB(0); sg0.p[1] = BB(1); sg0.p[2] = BB(2); sg0.p[3] = BB(3); sg0.p[4] = BB(4); sg0.p[5] = BB(5);
  gemm_wseg<0><<<dim3(2, 512), 256, 0, stream>>>(sg0, WG0, 768, gb0, h0, XGg, BB(6), BB(7), USIG, nullptr, nullptr, nullptr);

  // layer 0 cand s-chains (rh group)
  gemm_diff<<<dim3(64, 8), 256, 0, stream>>>(BB(6), S0b, BB(2));
  gemm_diff<<<dim3(64, 8), 256, 0, stream>>>(BB(2), S0b, BB(3));
  gemm_diff<<<dim3(64, 8), 256, 0, stream>>>(BB(6), S1b, BB(4));
  gemm_diff<<<dim3(64, 8), 256, 0, stream>>>(BB(4), S1b, BB(5));

  // CAND0 -> h0_new fp32 to out_h0; bf16 hi/lo layer-1 x0 into BB0/BB1
  Segs sc0{};
  sc0.p[0] = BB(6); sc0.p[1] = BB(7); sc0.p[2] = BB(2); sc0.p[3] = BB(3); sc0.p[4] = BB(4); sc0.p[5] = BB(5);
  gemm_wseg<1><<<dim3(1, 512), 256, 0, stream>>>(sc0, WC0, 768, cb0, h0, XGc, nullptr, nullptr, USIG, out_h0, BB(0), BB(1));

  // layer 1 x-group (h0_new) s-chains
  gemm_diff<<<dim3(64, 8), 256, 0, stream>>>(BB(0), S0b, BB(2));
  gemm_diff<<<dim3(64, 8), 256, 0, stream>>>(BB(2), S0b, BB(3));
  gemm_diff<<<dim3(64, 8), 256, 0, stream>>>(BB(0), S1b, BB(4));
  gemm_diff<<<dim3(64, 8), 256, 0, stream>>>(BB(4), S1b, BB(5));
  // layer 1 h-group (h1) s-chains
  gemm_diff<<<dim3(64, 8), 256, 0, stream>>>(OH1a, S0b, BB(6));
  gemm_diff<<<dim3(64, 8), 256, 0, stream>>>(BB(6), S0b, BB(7));
  gemm_diff<<<dim3(64, 8), 256, 0, stream>>>(OH1a, S1b, BB(8));
  gemm_diff<<<dim3(64, 8), 256, 0, stream>>>(BB(8), S1b, XS(0));

  // GATE1: rh1 -> XS1/XS2 (XG regions dead), u1 -> USIG
  Segs sg1{};
  sg1.p[0] = BB(0); sg1.p[1] = BB(1); sg1.p[2] = BB(2); sg1.p[3] = BB(3); sg1.p[4] = BB(4); sg1.p[5] = BB(5);
  sg1.p[6] = OH1a;  sg1.p[7] = OH1b;  sg1.p[8] = BB(6); sg1.p[9] = BB(7); sg1.p[10] = BB(8); sg1.p[11] = XS(0);
  gemm_wseg<0><<<dim3(2, 512), 256, 0, stream>>>(sg1, WG1, 1536, gb1, h1, nullptr, XS(1), XS(2), USIG, nullptr, nullptr, nullptr);

  // layer 1 cand s-chains (rh1 group)
  gemm_diff<<<dim3(64, 8), 256, 0, stream>>>(XS(1), S0b, BB(6));
  gemm_diff<<<dim3(64, 8), 256, 0, stream>>>(BB(6), S0b, BB(7));
  gemm_diff<<<dim3(64, 8), 256, 0, stream>>>(XS(1), S1b, BB(8));
  gemm_diff<<<dim3(64, 8), 256, 0, stream>>>(BB(8), S1b, XS(0));

  // CAND1 -> h1_new fp32 to out_h1 (OH1a/b dead)
  Segs sc1{};
  sc1.p[0] = BB(0); sc1.p[1] = BB(1); sc1.p[2] = BB(2); sc1.p[3] = BB(3); sc1.p[4] = BB(4); sc1.p[5] = BB(5);
  sc1.p[6] = XS(1); sc1.p[7] = XS(2); sc1.p[8] = BB(6); sc1.p[9] = BB(7); sc1.p[10] = BB(8); sc1.p[11] = XS(0);
  gemm_wseg<1><<<dim3(1, 512), 256, 0, stream>>>(sc1, WC1, 1536, cb1, h1, nullptr, nullptr, nullptr, USIG, out_h1, nullptr, nullptr);

  // projection
  proj_k<<<16384, 256, 0, stream>>>(out_h1, pw, pb, out);
}

// Round 6
// 1286.790 us; speedup vs baseline: 1.3997x; 1.3997x over previous
//
#include <hip/hip_runtime.h>
#include <hip/hip_bf16.h>

typedef unsigned short u16;
typedef unsigned int u32;
typedef __attribute__((ext_vector_type(2))) unsigned int u32x2;
typedef __attribute__((ext_vector_type(4))) float f32x4;
typedef __attribute__((ext_vector_type(8))) __bf16 bf16x8;

#define DEVI static __device__ __forceinline__

// ---------- scalar helpers ----------
DEVI u16 f2bf(float x) {
  union { float f; u32 u; } v; v.f = x;
  u32 r = v.u + 0x7fffu + ((v.u >> 16) & 1u);
  return (u16)(r >> 16);
}
DEVI float bf2f(u16 h) { union { u32 u; float f; } v; v.u = ((u32)h) << 16; return v.f; }
DEVI u32 pk2bf(float a, float b) { return (u32)f2bf(a) | ((u32)f2bf(b) << 16); }
DEVI float sigm(float x) { return 1.f / (1.f + __expf(-x)); }
DEVI float tanh_(float x) {
  float a = fabsf(x);
  float e = __expf(-2.f * a);
  float t = (1.f - e) / (1.f + e);
  return copysignf(t, x);
}

DEVI void gl_lds16(const u16* g, void* l) {
  __builtin_amdgcn_global_load_lds(
      (const __attribute__((address_space(1))) u32*)(const void*)g,
      (__attribute__((address_space(3))) u32*)l, 16, 0, 0);
}
DEVI f32x4 mfma16(bf16x8 a, bf16x8 b, f32x4 c) {
  return __builtin_amdgcn_mfma_f32_16x16x32_bf16(a, b, c, 0, 0, 0);
}

// ---------- prep kernels ----------
__global__ void sums_k(const float* __restrict__ adj, float* __restrict__ rs, float* __restrict__ cs) {
  __shared__ float red[256];
  int bid = blockIdx.x, tid = threadIdx.x;
  if (bid < 1024) {
    float a = 0.f;
    for (int j = tid; j < 1024; j += 256) a += adj[bid * 1024 + j];
    red[tid] = a; __syncthreads();
    for (int s = 128; s; s >>= 1) { if (tid < s) red[tid] += red[tid + s]; __syncthreads(); }
    if (!tid) rs[bid] = red[0];
  } else {
    int c0 = (bid - 1024) * 64;
    int c = tid & 63, r0 = tid >> 6;
    float a = 0.f;
    for (int r = r0; r < 1024; r += 4) a += adj[r * 1024 + c0 + c];
    red[tid] = a; __syncthreads();
    if (tid < 64) cs[c0 + c] = red[c] + red[64 + c] + red[128 + c] + red[192 + c];
  }
}

__global__ void s0_build(const float* __restrict__ adj, const float* __restrict__ rs, u16* __restrict__ S0) {
  __shared__ float tile[32][33];
  int i0 = blockIdx.x * 32, j0 = blockIdx.y * 32;
  int tx = threadIdx.x & 31, ty = threadIdx.x >> 5;
  for (int yy = ty; yy < 32; yy += 8)
    tile[yy][tx] = adj[(j0 + yy) * 1024 + i0 + tx];
  __syncthreads();
  for (int yy = ty; yy < 32; yy += 8)
    S0[(i0 + yy) * 1024 + j0 + tx] = f2bf(tile[tx][yy] / rs[j0 + tx]);
}

__global__ void s1_build(const float* __restrict__ adj, const float* __restrict__ cs, u16* __restrict__ S1) {
  int idx = blockIdx.x * 256 + threadIdx.x;
  int j = idx & 1023;
  S1[idx] = f2bf(adj[idx] / cs[j]);
}

// pack h-part weights with cheb-elimination fold; pure full segments.
__global__ void pack_w(const float* __restrict__ src, u16* __restrict__ dst,
                       int NO, int Ktot, int off0, int off1) {
  int idx = blockIdx.x * 256 + threadIdx.x;
  if (idx >= NO * Ktot) return;
  int o = idx / Ktot, k = idx % Ktot;
  int seg = k >> 7, i = k & 127;
  int mo = seg % 6;
  int pos = ((seg / 6) ? off1 : off0) + i;
  const float* wr = src + (long)pos * 5 * NO + o;
  float v;
  switch (mo) {
    case 0: case 1: v = wr[0] - wr[(long)2 * NO] - wr[(long)4 * NO]; break;
    case 2: v = wr[(long)1 * NO]; break;
    case 3: v = 2.f * wr[(long)2 * NO]; break;
    case 4: v = wr[(long)3 * NO]; break;
    default: v = 2.f * wr[(long)4 * NO]; break;
  }
  dst[idx] = f2bf(v);
}

// h (B, N*128) fp32 -> hiN/loN flat [r=b*1024+n][u] bf16 (same addr as src) + hiT [b*128+u][n]
__global__ void build_hx(const float* __restrict__ src, u16* __restrict__ hiN,
                         u16* __restrict__ loN, u16* __restrict__ hiT) {
  __shared__ u16 t[32][33];
  int n0 = blockIdx.x * 32, u0 = blockIdx.y * 32, b = blockIdx.z;
  int tx = threadIdx.x & 31, ty = threadIdx.x >> 5;
  for (int yy = ty; yy < 32; yy += 8) {
    long d = (long)b * 131072 + (n0 + yy) * 128 + u0 + tx;
    float v = src[d];
    u16 h = f2bf(v);
    hiN[d] = h;
    loN[d] = f2bf(v - bf2f(h));
    t[yy][tx] = h;
  }
  __syncthreads();
  for (int yy = ty; yy < 32; yy += 8)
    hiT[(long)(b * 128 + u0 + yy) * 1024 + n0 + tx] = t[tx][yy];
}

// ---------- x-part (layer 0): exact fp32 path ----------
__global__ void xch0_build(const float* __restrict__ inp, float* __restrict__ x0) {
  int idx = blockIdx.x * 256 + threadIdx.x;   // 131072
  int n = idx >> 7, c = idx & 127, b = c >> 1, d = c & 1;
  x0[idx] = inp[b * 2048 + n * 2 + d];
}

__global__ void xch_diffuse(const u16* __restrict__ S, const float* __restrict__ xin,
                            float* __restrict__ xout) {
  int n = blockIdx.x, c = threadIdx.x;
  float acc = 0.f;
  for (int k = 0; k < 1024; k++) acc += bf2f(S[n * 1024 + k]) * xin[k * 128 + c];
  xout[n * 128 + c] = acc;
}

__global__ void xch_cheb(const u16* __restrict__ S, const float* __restrict__ xin,
                         const float* __restrict__ x0, float* __restrict__ xout) {
  int n = blockIdx.x, c = threadIdx.x;
  float acc = 0.f;
  for (int k = 0; k < 1024; k++) acc += bf2f(S[n * 1024 + k]) * xin[k * 128 + c];
  xout[n * 128 + c] = 2.f * acc - x0[n * 128 + c];
}

// XG[r][o] with r = b*1024 + n
__global__ void xg_build(const float* __restrict__ gw0, const float* __restrict__ cw0,
                         const float* __restrict__ xch,
                         u16* __restrict__ xgg, u16* __restrict__ xgc) {
  int r = blockIdx.x;           // 65536
  int n = r & 1023, b = r >> 10;
  int t = threadIdx.x;          // 256
  __shared__ float xv[10];
  if (t < 10) { int m = t % 5, p = t / 5; xv[t] = xch[(long)m * 131072 + n * 128 + b * 2 + p]; }
  __syncthreads();
  float a = 0.f;
#pragma unroll
  for (int q = 0; q < 10; q++) { int m = q % 5, p = q / 5;
    a += gw0[(long)(p * 5 + m) * 256 + t] * xv[q]; }
  xgg[(long)r * 256 + t] = f2bf(a);
  if (t < 128) {
    float a2 = 0.f;
#pragma unroll
    for (int q = 0; q < 10; q++) { int m = q % 5, p = q / 5;
      a2 += cw0[(long)(p * 5 + m) * 128 + t] * xv[q]; }
    xgc[(long)r * 128 + t] = f2bf(a2);
  }
}

// ---------- fused diffusion GEMM:  Y[n][f] = sum_k S[n][k] * fT[f][k] ----------
// A-tile = S rows, B-tile = fT rows; both plain gl_lds staging (wseg-clone).
struct DiffJob { const u16* X; const u16* S; u16* YN; u16* YT; };
struct DiffJobs { DiffJob j[4]; };

__global__ __launch_bounds__(256) void gemm_diffz(DiffJobs jobs) {
  DiffJob J = jobs.j[blockIdx.z];
  __shared__ char smem[32768];
  const int tid = threadIdx.x, wid = tid >> 6, lane = tid & 63;
  const int wr = wid >> 1, wc = wid & 1, l15 = lane & 15, l4 = lane >> 4;
  const int ntile = blockIdx.y * 128;
  const int fbase = blockIdx.x * 128;
  char* A0 = smem;          char* A1 = smem + 8192;
  char* B0 = smem + 16384;  char* B1 = smem + 24576;
  const int s_row = lane >> 2, s_kcp = lane & 3;

  f32x4 acc[4][4];
#pragma unroll
  for (int i = 0; i < 4; i++)
#pragma unroll
    for (int j = 0; j < 4; j++) acc[i][j] = (f32x4){0.f, 0.f, 0.f, 0.f};

  auto stage = [&](char* Ab, char* Bb, int ks) {
    const int k0 = ks * 32;
#pragma unroll
    for (int c = 0; c < 2; c++) {
      const int bb = wid * 2 + c;
      const int row = bb * 16 + s_row;
      const int sw = (s_kcp ^ (row & 3)) * 8;
      gl_lds16(J.S + (long)(ntile + row) * 1024 + k0 + sw, Ab + bb * 1024);
      gl_lds16(J.X + (long)(fbase + row) * 1024 + k0 + sw, Bb + bb * 1024);
    }
  };

  stage(A0, B0, 0);
  __syncthreads();
  char* cA = A0; char* cB = B0; char* nA = A1; char* nB = B1;
  for (int ks = 0; ks < 32; ks++) {
    if (ks < 31) stage(nA, nB, ks + 1);
    bf16x8 af[4], bfr[4];
#pragma unroll
    for (int mb = 0; mb < 4; mb++) {
      const int row = wr * 64 + mb * 16 + l15;
      af[mb] = *(const bf16x8*)(cA + row * 64 + ((l4 ^ (row & 3)) * 16));
    }
#pragma unroll
    for (int nb = 0; nb < 4; nb++) {
      const int row = wc * 64 + nb * 16 + l15;
      bfr[nb] = *(const bf16x8*)(cB + row * 64 + ((l4 ^ (row & 3)) * 16));
    }
#pragma unroll
    for (int mb = 0; mb < 4; mb++)
#pragma unroll
      for (int nb = 0; nb < 4; nb++)
        acc[mb][nb] = mfma16(af[mb], bfr[nb], acc[mb][nb]);
    __syncthreads();
    { char* t = cA; cA = nA; nA = t; t = cB; cB = nB; nB = t; }
  }

#pragma unroll
  for (int mb = 0; mb < 4; mb++) {
#pragma unroll
    for (int nb = 0; nb < 4; nb++) {
      const int n0 = ntile + wr * 64 + mb * 16 + l4 * 4;
      const int f  = fbase + wc * 64 + nb * 16 + l15;
      const int b = f >> 7, u = f & 127;
      f32x4 v = acc[mb][nb];
      u16 h0 = f2bf(v[0]), h1 = f2bf(v[1]), h2 = f2bf(v[2]), h3 = f2bf(v[3]);
      u16* yn = J.YN + (long)b * 131072 + (long)n0 * 128 + u;
      yn[0] = h0; yn[128] = h1; yn[256] = h2; yn[384] = h3;
      if (J.YT != nullptr) {
        u32x2 wv; wv[0] = (u32)h0 | ((u32)h1 << 16); wv[1] = (u32)h2 | ((u32)h3 << 16);
        *(u32x2*)(J.YT + (long)f * 1024 + n0) = wv;
      }
    }
  }
}

// ---------- W GEMM with fused epilogue (r = b*1024+n; segments flat [r][128]) ----------
struct Segs { const u16* p[12]; };
DEVI const u16* seg_sel(const Segs& s, int i) {
  switch (i) {
    case 0: return s.p[0]; case 1: return s.p[1]; case 2: return s.p[2];
    case 3: return s.p[3]; case 4: return s.p[4]; case 5: return s.p[5];
    case 6: return s.p[6]; case 7: return s.p[7]; case 8: return s.p[8];
    case 9: return s.p[9]; case 10: return s.p[10]; default: return s.p[11];
  }
}

template<int EPI>   // 0 = GATE (sigmoid -> r*h split N+T, u bf16), 1 = CAND (tanh -> hnew)
__global__ __launch_bounds__(256) void gemm_wseg(
    Segs segs, const u16* __restrict__ WT, int Ktot,
    const float* __restrict__ bias, const float* __restrict__ Hprev,
    const u16* __restrict__ xadd,
    u16* __restrict__ rh_hi, u16* __restrict__ rh_lo, u16* __restrict__ rh_t,
    u16* __restrict__ usig,
    float* __restrict__ hnew_out, u16* __restrict__ xa_hi, u16* __restrict__ xa_lo,
    u16* __restrict__ xa_t)
{
  __shared__ char smem[32768];
  const int tid = threadIdx.x, wid = tid >> 6, lane = tid & 63;
  const int wr = wid >> 1, wc = wid & 1, l15 = lane & 15, l4 = lane >> 4;
  const int otile = blockIdx.x * 128, rtile = blockIdx.y * 128;
  char* A0 = smem;          char* A1 = smem + 8192;
  char* B0 = smem + 16384;  char* B1 = smem + 24576;
  const int s_row = lane >> 2, s_kcp = lane & 3;

  f32x4 acc[4][4];
#pragma unroll
  for (int i = 0; i < 4; i++)
#pragma unroll
    for (int j = 0; j < 4; j++) acc[i][j] = (f32x4){0.f, 0.f, 0.f, 0.f};

  const int NKS = Ktot >> 5;
  auto stage = [&](char* Ab, char* Bb, int ks) {
    const int k0 = ks * 32;
    const int sidx = ks >> 2, si0 = (ks & 3) * 32;
    const u16* sp = seg_sel(segs, sidx);
#pragma unroll
    for (int c = 0; c < 2; c++) {
      const int bb = wid * 2 + c;
      const int arow = bb * 16 + s_row;
      gl_lds16(WT + (long)(otile + arow) * Ktot + k0 + ((s_kcp ^ (arow & 3)) * 8), Ab + bb * 1024);
      const int r = rtile + bb * 16 + s_row;
      gl_lds16(sp + (long)r * 128 + si0 + ((s_kcp ^ (r & 3)) * 8), Bb + bb * 1024);
    }
  };

  stage(A0, B0, 0);
  __syncthreads();
  char* cA = A0; char* cB = B0; char* nA = A1; char* nB = B1;
  for (int ks = 0; ks < NKS; ks++) {
    if (ks + 1 < NKS) stage(nA, nB, ks + 1);
    bf16x8 af[4], bfr[4];
#pragma unroll
    for (int mb = 0; mb < 4; mb++) {
      const int row = wr * 64 + mb * 16 + l15;
      af[mb] = *(const bf16x8*)(cA + row * 64 + ((l4 ^ (row & 3)) * 16));
    }
#pragma unroll
    for (int nb = 0; nb < 4; nb++) {
      const int row = wc * 64 + nb * 16 + l15;
      bfr[nb] = *(const bf16x8*)(cB + row * 64 + ((l4 ^ (row & 3)) * 16));
    }
#pragma unroll
    for (int mb = 0; mb < 4; mb++)
#pragma unroll
      for (int nb = 0; nb < 4; nb++)
        acc[mb][nb] = mfma16(af[mb], bfr[nb], acc[mb][nb]);
    __syncthreads();
    { char* t = cA; cA = nA; nA = t; t = cB; cB = nB; nB = t; }
  }

#pragma unroll
  for (int mb = 0; mb < 4; mb++) {
#pragma unroll
    for (int nb = 0; nb < 4; nb++) {
      const int o = otile + wr * 64 + mb * 16 + l4 * 4;
      const int rr = rtile + wc * 64 + nb * 16 + l15;
      const int n = rr & 1023, b = rr >> 10;
      f32x4 v = acc[mb][nb];
      float4 bv = *(const float4*)(bias + o);
      float a0 = 0.f, a1 = 0.f, a2 = 0.f, a3 = 0.f;
      if (xadd != nullptr) {
        const int xs = (EPI == 0) ? 256 : 128;
        u32x2 xv = *(const u32x2*)(xadd + (long)rr * xs + o);
        a0 = bf2f((u16)(xv[0] & 0xffffu)); a1 = bf2f((u16)(xv[0] >> 16));
        a2 = bf2f((u16)(xv[1] & 0xffffu)); a3 = bf2f((u16)(xv[1] >> 16));
      }
      if (EPI == 0) {
        float s0 = sigm(v[0] + bv.x + a0), s1 = sigm(v[1] + bv.y + a1);
        float s2 = sigm(v[2] + bv.z + a2), s3 = sigm(v[3] + bv.w + a3);
        if (o < 128) {
          float4 hv = *(const float4*)(Hprev + (long)rr * 128 + o);
          float r0 = s0 * hv.x, r1 = s1 * hv.y, r2 = s2 * hv.z, r3 = s3 * hv.w;
          u16 h0 = f2bf(r0), h1 = f2bf(r1), h2 = f2bf(r2), h3 = f2bf(r3);
          long d = (long)rr * 128 + o;
          u32x2 wh; wh[0] = (u32)h0 | ((u32)h1 << 16); wh[1] = (u32)h2 | ((u32)h3 << 16);
          *(u32x2*)(rh_hi + d) = wh;
          u32x2 wl; wl[0] = pk2bf(r0 - bf2f(h0), r1 - bf2f(h1));
          wl[1] = pk2bf(r2 - bf2f(h2), r3 - bf2f(h3));
          *(u32x2*)(rh_lo + d) = wl;
          u16* rt = rh_t + (long)(b * 128 + o) * 1024 + n;
          rt[0] = h0; rt[1024] = h1; rt[2048] = h2; rt[3072] = h3;
        } else {
          u32x2 wu; wu[0] = pk2bf(s0, s1); wu[1] = pk2bf(s2, s3);
          *(u32x2*)(usig + (long)rr * 128 + (o - 128)) = wu;
        }
      } else {
        float c0 = tanh_(v[0] + bv.x + a0), c1 = tanh_(v[1] + bv.y + a1);
        float c2 = tanh_(v[2] + bv.z + a2), c3 = tanh_(v[3] + bv.w + a3);
        u32x2 uv = *(const u32x2*)(usig + (long)rr * 128 + o);
        float u0 = bf2f((u16)(uv[0] & 0xffffu)), u1 = bf2f((u16)(uv[0] >> 16));
        float u2 = bf2f((u16)(uv[1] & 0xffffu)), u3 = bf2f((u16)(uv[1] >> 16));
        float4 hv = *(const float4*)(Hprev + (long)rr * 128 + o);
        float h0n = u0 * hv.x + (1.f - u0) * c0;
        float h1n = u1 * hv.y + (1.f - u1) * c1;
        float h2n = u2 * hv.z + (1.f - u2) * c2;
        float h3n = u3 * hv.w + (1.f - u3) * c3;
        *(float4*)(hnew_out + (long)rr * 128 + o) = make_float4(h0n, h1n, h2n, h3n);
        if (xa_hi != nullptr) {
          u16 x0 = f2bf(h0n), x1 = f2bf(h1n), x2 = f2bf(h2n), x3 = f2bf(h3n);
          long d = (long)rr * 128 + o;
          u32x2 wh; wh[0] = (u32)x0 | ((u32)x1 << 16); wh[1] = (u32)x2 | ((u32)x3 << 16);
          *(u32x2*)(xa_hi + d) = wh;
          u32x2 wl; wl[0] = pk2bf(h0n - bf2f(x0), h1n - bf2f(x1));
          wl[1] = pk2bf(h2n - bf2f(x2), h3n - bf2f(x3));
          *(u32x2*)(xa_lo + d) = wl;
          u16* xt = xa_t + (long)(b * 128 + o) * 1024 + n;
          xt[0] = x0; xt[1024] = x1; xt[2048] = x2; xt[3072] = x3;
        }
      }
    }
  }
}

// ---------- projection ----------
__global__ __launch_bounds__(256) void proj_k(const float* __restrict__ h1n, const float* __restrict__ pw,
                                              const float* __restrict__ pb, float* __restrict__ out) {
  int wid = threadIdx.x >> 6, lane = threadIdx.x & 63;
  int r = blockIdx.x * 4 + wid;
  int b = r >> 10, n = r & 1023;
  const float* hp = h1n + (long)b * 131072 + n * 128;
  float ha = hp[lane], hb = hp[lane + 64];
  float p0 = ha * pw[lane * 2]     + hb * pw[(lane + 64) * 2];
  float p1 = ha * pw[lane * 2 + 1] + hb * pw[(lane + 64) * 2 + 1];
  for (int off = 32; off; off >>= 1) { p0 += __shfl_down(p0, off); p1 += __shfl_down(p1, off); }
  if (!lane) {
    out[(long)b * 2048 + n * 2]     = p0 + pb[0];
    out[(long)b * 2048 + n * 2 + 1] = p1 + pb[1];
  }
}

// ---------- host ----------
extern "C" void kernel_launch(void* const* d_in, const int* in_sizes, int n_in,
                              void* d_out, int out_size, void* d_ws, size_t ws_size,
                              hipStream_t stream) {
  (void)in_sizes; (void)n_in; (void)out_size; (void)ws_size;
  const float* inputs = (const float*)d_in[0];
  const float* hidden = (const float*)d_in[1];
  const float* adj    = (const float*)d_in[2];
  const float* gw0 = (const float*)d_in[3];
  const float* gb0 = (const float*)d_in[4];
  const float* cw0 = (const float*)d_in[5];
  const float* cb0 = (const float*)d_in[6];
  const float* gw1 = (const float*)d_in[7];
  const float* gb1 = (const float*)d_in[8];
  const float* cw1 = (const float*)d_in[9];
  const float* cb1 = (const float*)d_in[10];
  const float* pw  = (const float*)d_in[11];
  const float* pb  = (const float*)d_in[12];

  float* out    = (float*)d_out;
  float* out_h0 = out + 131072;
  float* out_h1 = out_h0 + 8388608;
  const float* h0 = hidden;
  const float* h1 = hidden + 8388608;

  u16* OH1a = (u16*)out_h1;            // h1 hiN
  u16* OH1b = OH1a + 8388608;          // h1 loN

  char* wp = (char*)d_ws;
  auto alloc = [&](size_t bytes) { char* r = wp; wp += (bytes + 255) & ~(size_t)255; return r; };
  u16*   S0b  = (u16*)  alloc(1048576 * 2);
  u16*   S1b  = (u16*)  alloc(1048576 * 2);
  float* rs   = (float*)alloc(1024 * 4);
  float* cs   = (float*)alloc(1024 * 4);
  u16*   WG0  = (u16*)  alloc((size_t)256 * 768 * 2);
  u16*   WC0  = (u16*)  alloc((size_t)128 * 768 * 2);
  u16*   WG1  = (u16*)  alloc((size_t)256 * 1536 * 2);
  u16*   WC1  = (u16*)  alloc((size_t)128 * 1536 * 2);
  u16*   Bb   = (u16*)  alloc((size_t)13 * 8388608 * 2);   // 13 chain slots
  u16*   USIG = (u16*)  alloc((size_t)8388608 * 2);
  float* XCH  = (float*)alloc((size_t)5 * 131072 * 4);
  auto BB = [&](int i) { return Bb + (size_t)i * 8388608; };
  auto XC = [&](int i) { return XCH + (size_t)i * 131072; };
  // slots: A=0 B=1 C=2 D=3 E=4 F=5 G=6 H=7 I=8 J=9 K=10 L=11 M=12
  u16* XGg = BB(4);   // spans slots 4,5 (33.5 MB)
  u16* XGc = BB(6);

  // prep
  sums_k<<<1040, 256, 0, stream>>>(adj, rs, cs);
  s0_build<<<dim3(32, 32), 256, 0, stream>>>(adj, rs, S0b);
  s1_build<<<4096, 256, 0, stream>>>(adj, cs, S1b);
  pack_w<<<768,  256, 0, stream>>>(gw0, WG0, 256, 768, 2, 0);
  pack_w<<<384,  256, 0, stream>>>(cw0, WC0, 128, 768, 2, 0);
  pack_w<<<1536, 256, 0, stream>>>(gw1, WG1, 256, 1536, 0, 128);
  pack_w<<<768,  256, 0, stream>>>(cw1, WC1, 128, 1536, 0, 128);
  build_hx<<<dim3(32, 4, 64), 256, 0, stream>>>(h0, BB(0), BB(1), BB(2));      // A,B + x0T->C
  build_hx<<<dim3(32, 4, 64), 256, 0, stream>>>(h1, OH1a, OH1b, BB(3));        // h1T->D

  // x-part exact chains + additive preacts
  xch0_build<<<512, 256, 0, stream>>>(inputs, XC(0));
  xch_diffuse<<<1024, 128, 0, stream>>>(S0b, XC(0), XC(1));
  xch_cheb   <<<1024, 128, 0, stream>>>(S0b, XC(1), XC(0), XC(2));
  xch_diffuse<<<1024, 128, 0, stream>>>(S1b, XC(0), XC(3));
  xch_cheb   <<<1024, 128, 0, stream>>>(S1b, XC(3), XC(0), XC(4));
  xg_build<<<65536, 256, 0, stream>>>(gw0, cw0, XCH, XGg, XGc);

  DiffJobs dj{};
  // L0 s-chain: {s1: S0*x0T -> H(+T I) ; s3: S1*x0T -> J(+T K)}
  dj.j[0] = {BB(2), S0b, BB(7), BB(8)};
  dj.j[1] = {BB(2), S1b, BB(9), BB(10)};
  gemm_diffz<<<dim3(64, 8, 2), 256, 0, stream>>>(dj);
  // {s2: S0*s1T -> L ; s4: S1*s3T -> M}
  dj.j[0] = {BB(8),  S0b, BB(11), nullptr};
  dj.j[1] = {BB(10), S1b, BB(12), nullptr};
  gemm_diffz<<<dim3(64, 8, 2), 256, 0, stream>>>(dj);

  // GATE0: segs {A,B,H,L,J,M}; rhN->C, rhlo->K, rhT->I
  Segs sg0{};
  sg0.p[0] = BB(0); sg0.p[1] = BB(1); sg0.p[2] = BB(7); sg0.p[3] = BB(11); sg0.p[4] = BB(9); sg0.p[5] = BB(12);
  gemm_wseg<0><<<dim3(2, 512), 256, 0, stream>>>(sg0, WG0, 768, gb0, h0, XGg,
      BB(2), BB(10), BB(8), USIG, nullptr, nullptr, nullptr, nullptr);

  // L0 c-chain: {c1: S0*rhT -> E(+T F) ; c3: S1*rhT -> A(+T B)}
  dj.j[0] = {BB(8), S0b, BB(4), BB(5)};
  dj.j[1] = {BB(8), S1b, BB(0), BB(1)};
  gemm_diffz<<<dim3(64, 8, 2), 256, 0, stream>>>(dj);
  // {c2: S0*c1T -> H ; c4: S1*c3T -> J}
  dj.j[0] = {BB(5), S0b, BB(7), nullptr};
  dj.j[1] = {BB(1), S1b, BB(9), nullptr};
  gemm_diffz<<<dim3(64, 8, 2), 256, 0, stream>>>(dj);

  // CAND0: segs {C,K,E,H,A,J}; xadd=XGc; out_h0; xaN->L, xalo->M, xaT->B
  Segs sc0{};
  sc0.p[0] = BB(2); sc0.p[1] = BB(10); sc0.p[2] = BB(4); sc0.p[3] = BB(7); sc0.p[4] = BB(0); sc0.p[5] = BB(9);
  gemm_wseg<1><<<dim3(1, 512), 256, 0, stream>>>(sc0, WC0, 768, cb0, h0, XGc,
      nullptr, nullptr, nullptr, USIG, out_h0, BB(11), BB(12), BB(1));

  // L1 wave-1 (z=4): {s1': S0*xaT -> A(+T C) ; s3': S1*xaT -> E(+T F) ; t1: S0*h1T -> I(+T G) ; t3: S1*h1T -> J(+T H)}
  dj.j[0] = {BB(1), S0b, BB(0), BB(2)};
  dj.j[1] = {BB(1), S1b, BB(4), BB(5)};
  dj.j[2] = {BB(3), S0b, BB(8), BB(6)};
  dj.j[3] = {BB(3), S1b, BB(9), BB(7)};
  gemm_diffz<<<dim3(64, 8, 4), 256, 0, stream>>>(dj);
  // {s2': S0*s1'T -> K ; s4': S1*s3'T -> D}
  dj.j[0] = {BB(2), S0b, BB(10), nullptr};
  dj.j[1] = {BB(5), S1b, BB(3),  nullptr};
  gemm_diffz<<<dim3(64, 8, 2), 256, 0, stream>>>(dj);
  // {t2: S0*t1T -> B ; t4: S1*t3T -> C}
  dj.j[0] = {BB(6), S0b, BB(1), nullptr};
  dj.j[1] = {BB(7), S1b, BB(2), nullptr};
  gemm_diffz<<<dim3(64, 8, 2), 256, 0, stream>>>(dj);

  // GATE1: segs x{L,M,A,K,E,D} h{OH1a,OH1b,I,B,J,C}; rh1N->F, rh1lo->H, rh1T->G
  Segs sg1{};
  sg1.p[0] = BB(11); sg1.p[1] = BB(12); sg1.p[2] = BB(0); sg1.p[3] = BB(10); sg1.p[4] = BB(4); sg1.p[5] = BB(3);
  sg1.p[6] = OH1a;   sg1.p[7] = OH1b;   sg1.p[8] = BB(8); sg1.p[9] = BB(1);  sg1.p[10] = BB(9); sg1.p[11] = BB(2);
  gemm_wseg<0><<<dim3(2, 512), 256, 0, stream>>>(sg1, WG1, 1536, gb1, h1, nullptr,
      BB(5), BB(7), BB(6), USIG, nullptr, nullptr, nullptr, nullptr);

  // L1 d-chain: {d1: S0*rh1T -> I(+T B) ; d3: S1*rh1T -> J(+T C)}
  dj.j[0] = {BB(6), S0b, BB(8), BB(1)};
  dj.j[1] = {BB(6), S1b, BB(9), BB(2)};
  gemm_diffz<<<dim3(64, 8, 2), 256, 0, stream>>>(dj);
  // d2: S0*d1T -> G
  dj.j[0] = {BB(1), S0b, BB(6), nullptr};
  gemm_diffz<<<dim3(64, 8, 1), 256, 0, stream>>>(dj);
  // d4: S1*d3T -> B
  dj.j[0] = {BB(2), S1b, BB(1), nullptr};
  gemm_diffz<<<dim3(64, 8, 1), 256, 0, stream>>>(dj);

  // CAND1: segs x{L,M,A,K,E,D} rh{F,H,I,G,J,B}; Hprev=h1 -> out_h1
  Segs sc1{};
  sc1.p[0] = BB(11); sc1.p[1] = BB(12); sc1.p[2] = BB(0); sc1.p[3] = BB(10); sc1.p[4] = BB(4); sc1.p[5] = BB(3);
  sc1.p[6] = BB(5);  sc1.p[7] = BB(7);  sc1.p[8] = BB(8); sc1.p[9] = BB(6);  sc1.p[10] = BB(9); sc1.p[11] = BB(1);
  gemm_wseg<1><<<dim3(1, 512), 256, 0, stream>>>(sc1, WC1, 1536, cb1, h1, nullptr,
      nullptr, nullptr, nullptr, USIG, out_h1, nullptr, nullptr, nullptr);

  // projection
  proj_k<<<16384, 256, 0, stream>>>(out_h1, pw, pb, out);
}

// Round 7
// 1179.760 us; speedup vs baseline: 1.5267x; 1.0907x over previous
//
#include <hip/hip_runtime.h>
#include <hip/hip_bf16.h>

typedef unsigned short u16;
typedef unsigned int u32;
typedef __attribute__((ext_vector_type(2))) unsigned int u32x2;
typedef __attribute__((ext_vector_type(4))) float f32x4;
typedef __attribute__((ext_vector_type(8))) __bf16 bf16x8;

#define DEVI static __device__ __forceinline__

// ---------- scalar helpers ----------
DEVI u16 f2bf(float x) {
  union { float f; u32 u; } v; v.f = x;
  u32 r = v.u + 0x7fffu + ((v.u >> 16) & 1u);
  return (u16)(r >> 16);
}
DEVI float bf2f(u16 h) { union { u32 u; float f; } v; v.u = ((u32)h) << 16; return v.f; }
DEVI u32 pk2bf(float a, float b) { return (u32)f2bf(a) | ((u32)f2bf(b) << 16); }
DEVI float sigm(float x) { return 1.f / (1.f + __expf(-x)); }
DEVI float tanh_(float x) {
  float a = fabsf(x);
  float e = __expf(-2.f * a);
  float t = (1.f - e) / (1.f + e);
  return copysignf(t, x);
}

DEVI void gl_lds16(const u16* g, void* l) {
  __builtin_amdgcn_global_load_lds(
      (const __attribute__((address_space(1))) u32*)(const void*)g,
      (__attribute__((address_space(3))) u32*)l, 16, 0, 0);
}
DEVI f32x4 mfma16(bf16x8 a, bf16x8 b, f32x4 c) {
  return __builtin_amdgcn_mfma_f32_16x16x32_bf16(a, b, c, 0, 0, 0);
}

// ---------- prep kernels ----------
__global__ void sums_k(const float* __restrict__ adj, float* __restrict__ rs, float* __restrict__ cs) {
  __shared__ float red[256];
  int bid = blockIdx.x, tid = threadIdx.x;
  if (bid < 1024) {
    float a = 0.f;
    for (int j = tid; j < 1024; j += 256) a += adj[bid * 1024 + j];
    red[tid] = a; __syncthreads();
    for (int s = 128; s; s >>= 1) { if (tid < s) red[tid] += red[tid + s]; __syncthreads(); }
    if (!tid) rs[bid] = red[0];
  } else {
    int c0 = (bid - 1024) * 64;
    int c = tid & 63, r0 = tid >> 6;
    float a = 0.f;
    for (int r = r0; r < 1024; r += 4) a += adj[r * 1024 + c0 + c];
    red[tid] = a; __syncthreads();
    if (tid < 64) cs[c0 + c] = red[c] + red[64 + c] + red[128 + c] + red[192 + c];
  }
}

__global__ void s0_build(const float* __restrict__ adj, const float* __restrict__ rs, u16* __restrict__ S0) {
  __shared__ float tile[32][33];
  int i0 = blockIdx.x * 32, j0 = blockIdx.y * 32;
  int tx = threadIdx.x & 31, ty = threadIdx.x >> 5;
  for (int yy = ty; yy < 32; yy += 8)
    tile[yy][tx] = adj[(j0 + yy) * 1024 + i0 + tx];
  __syncthreads();
  for (int yy = ty; yy < 32; yy += 8)
    S0[(i0 + yy) * 1024 + j0 + tx] = f2bf(tile[tx][yy] / rs[j0 + tx]);
}

__global__ void s1_build(const float* __restrict__ adj, const float* __restrict__ cs, u16* __restrict__ S1) {
  int idx = blockIdx.x * 256 + threadIdx.x;
  int j = idx & 1023;
  S1[idx] = f2bf(adj[idx] / cs[j]);
}

// pack h-part weights with cheb-elimination fold; pure full segments.
__global__ void pack_w(const float* __restrict__ src, u16* __restrict__ dst,
                       int NO, int Ktot, int off0, int off1) {
  int idx = blockIdx.x * 256 + threadIdx.x;
  if (idx >= NO * Ktot) return;
  int o = idx / Ktot, k = idx % Ktot;
  int seg = k >> 7, i = k & 127;
  int mo = seg % 6;
  int pos = ((seg / 6) ? off1 : off0) + i;
  const float* wr = src + (long)pos * 5 * NO + o;
  float v;
  switch (mo) {
    case 0: case 1: v = wr[0] - wr[(long)2 * NO] - wr[(long)4 * NO]; break;
    case 2: v = wr[(long)1 * NO]; break;
    case 3: v = 2.f * wr[(long)2 * NO]; break;
    case 4: v = wr[(long)3 * NO]; break;
    default: v = 2.f * wr[(long)4 * NO]; break;
  }
  dst[idx] = f2bf(v);
}

// h (B, N*128) fp32 -> hiN/loN flat [r=b*1024+n][u] bf16 + hiT [b*128+u][n]
__global__ void build_hx(const float* __restrict__ src, u16* __restrict__ hiN,
                         u16* __restrict__ loN, u16* __restrict__ hiT) {
  __shared__ u16 t[32][33];
  int n0 = blockIdx.x * 32, u0 = blockIdx.y * 32, b = blockIdx.z;
  int tx = threadIdx.x & 31, ty = threadIdx.x >> 5;
  for (int yy = ty; yy < 32; yy += 8) {
    long d = (long)b * 131072 + (n0 + yy) * 128 + u0 + tx;
    float v = src[d];
    u16 h = f2bf(v);
    hiN[d] = h;
    loN[d] = f2bf(v - bf2f(h));
    t[yy][tx] = h;
  }
  __syncthreads();
  for (int yy = ty; yy < 32; yy += 8)
    hiT[(long)(b * 128 + u0 + yy) * 1024 + n0 + tx] = t[tx][yy];
}

// ---------- x-part (layer 0): exact fp32 path ----------
__global__ void xch0_build(const float* __restrict__ inp, float* __restrict__ x0) {
  int idx = blockIdx.x * 256 + threadIdx.x;   // 131072
  int n = idx >> 7, c = idx & 127, b = c >> 1, d = c & 1;
  x0[idx] = inp[b * 2048 + n * 2 + d];
}

__global__ void xch_diffuse(const u16* __restrict__ S, const float* __restrict__ xin,
                            float* __restrict__ xout) {
  int n = blockIdx.x, c = threadIdx.x;
  float acc = 0.f;
  for (int k = 0; k < 1024; k++) acc += bf2f(S[n * 1024 + k]) * xin[k * 128 + c];
  xout[n * 128 + c] = acc;
}

__global__ void xch_cheb(const u16* __restrict__ S, const float* __restrict__ xin,
                         const float* __restrict__ x0, float* __restrict__ xout) {
  int n = blockIdx.x, c = threadIdx.x;
  float acc = 0.f;
  for (int k = 0; k < 1024; k++) acc += bf2f(S[n * 1024 + k]) * xin[k * 128 + c];
  xout[n * 128 + c] = 2.f * acc - x0[n * 128 + c];
}

// XG[r][o] with r = b*1024 + n
__global__ void xg_build(const float* __restrict__ gw0, const float* __restrict__ cw0,
                         const float* __restrict__ xch,
                         u16* __restrict__ xgg, u16* __restrict__ xgc) {
  int r = blockIdx.x;           // 65536
  int n = r & 1023, b = r >> 10;
  int t = threadIdx.x;          // 256
  __shared__ float xv[10];
  if (t < 10) { int m = t % 5, p = t / 5; xv[t] = xch[(long)m * 131072 + n * 128 + b * 2 + p]; }
  __syncthreads();
  float a = 0.f;
#pragma unroll
  for (int q = 0; q < 10; q++) { int m = q % 5, p = q / 5;
    a += gw0[(long)(p * 5 + m) * 256 + t] * xv[q]; }
  xgg[(long)r * 256 + t] = f2bf(a);
  if (t < 128) {
    float a2 = 0.f;
#pragma unroll
    for (int q = 0; q < 10; q++) { int m = q % 5, p = q / 5;
      a2 += cw0[(long)(p * 5 + m) * 128 + t] * xv[q]; }
    xgc[(long)r * 128 + t] = f2bf(a2);
  }
}

// ---------- fused diffusion GEMM:  Y[n][f] = sum_k S[n][k] * fT[f][k] ----------
// Triple-buffered counted-vmcnt pipeline (no vmcnt(0) drain in main loop).
struct DiffJob { const u16* X; const u16* S; u16* YN; u16* YT; };
struct DiffJobs { DiffJob j[4]; };

__global__ __launch_bounds__(256) void gemm_diffz(DiffJobs jobs) {
  DiffJob J = jobs.j[blockIdx.z];
  __shared__ char smem[49152];
  const int tid = threadIdx.x, wid = tid >> 6, lane = tid & 63;
  const int wr = wid >> 1, wc = wid & 1, l15 = lane & 15, l4 = lane >> 4;
  const int ntile = blockIdx.y * 128;
  const int fbase = blockIdx.x * 128;
  char* A0 = smem;          char* A1 = smem + 8192;  char* A2 = smem + 16384;
  char* B0 = smem + 24576;  char* B1 = smem + 32768; char* B2 = smem + 40960;
  const int s_row = lane >> 2, s_kcp = lane & 3;

  f32x4 acc[4][4];
#pragma unroll
  for (int i = 0; i < 4; i++)
#pragma unroll
    for (int j = 0; j < 4; j++) acc[i][j] = (f32x4){0.f, 0.f, 0.f, 0.f};

  auto stage = [&](char* Ab, char* Bb, int ks) {
    const int k0 = ks * 32;
#pragma unroll
    for (int c = 0; c < 2; c++) {
      const int bb = wid * 2 + c;
      const int row = bb * 16 + s_row;
      const int sw = (s_kcp ^ (row & 3)) * 8;
      gl_lds16(J.S + (long)(ntile + row) * 1024 + k0 + sw, Ab + bb * 1024);
      gl_lds16(J.X + (long)(fbase + row) * 1024 + k0 + sw, Bb + bb * 1024);
    }
  };
  auto compute = [&](char* Ab, char* Bb) {
    bf16x8 af[4], bfr[4];
#pragma unroll
    for (int mb = 0; mb < 4; mb++) {
      const int row = wr * 64 + mb * 16 + l15;
      af[mb] = *(const bf16x8*)(Ab + row * 64 + ((l4 ^ (row & 3)) * 16));
    }
#pragma unroll
    for (int nb = 0; nb < 4; nb++) {
      const int row = wc * 64 + nb * 16 + l15;
      bfr[nb] = *(const bf16x8*)(Bb + row * 64 + ((l4 ^ (row & 3)) * 16));
    }
#pragma unroll
    for (int mb = 0; mb < 4; mb++)
#pragma unroll
      for (int nb = 0; nb < 4; nb++)
        acc[mb][nb] = mfma16(af[mb], bfr[nb], acc[mb][nb]);
  };

  const int NKS = 32;
  stage(A0, B0, 0);
  stage(A1, B1, 1);
  char* cA = A0; char* cB = B0;
  char* mA = A1; char* mB = B1;
  char* fA = A2; char* fB = B2;
  for (int ks = 0; ks + 2 < NKS; ks++) {
    stage(fA, fB, ks + 2);
    asm volatile("s_waitcnt vmcnt(8)" ::: "memory");
    __builtin_amdgcn_s_barrier();
    __builtin_amdgcn_sched_barrier(0);
    compute(cA, cB);
    asm volatile("" ::: "memory");
    __builtin_amdgcn_s_barrier();
    __builtin_amdgcn_sched_barrier(0);
    char* t = cA; cA = mA; mA = fA; fA = t;
    t = cB; cB = mB; mB = fB; fB = t;
  }
  asm volatile("s_waitcnt vmcnt(4)" ::: "memory");
  __builtin_amdgcn_s_barrier();
  __builtin_amdgcn_sched_barrier(0);
  compute(cA, cB);
  asm volatile("s_waitcnt vmcnt(0)" ::: "memory");
  __builtin_amdgcn_s_barrier();
  __builtin_amdgcn_sched_barrier(0);
  compute(mA, mB);

#pragma unroll
  for (int mb = 0; mb < 4; mb++) {
#pragma unroll
    for (int nb = 0; nb < 4; nb++) {
      const int n0 = ntile + wr * 64 + mb * 16 + l4 * 4;
      const int f  = fbase + wc * 64 + nb * 16 + l15;
      const int b = f >> 7, u = f & 127;
      f32x4 v = acc[mb][nb];
      u16 h0 = f2bf(v[0]), h1 = f2bf(v[1]), h2 = f2bf(v[2]), h3 = f2bf(v[3]);
      u16* yn = J.YN + (long)b * 131072 + (long)n0 * 128 + u;
      yn[0] = h0; yn[128] = h1; yn[256] = h2; yn[384] = h3;
      if (J.YT != nullptr) {
        u32x2 wv; wv[0] = (u32)h0 | ((u32)h1 << 16); wv[1] = (u32)h2 | ((u32)h3 << 16);
        *(u32x2*)(J.YT + (long)f * 1024 + n0) = wv;
      }
    }
  }
}

// ---------- W GEMM with fused epilogue (r = b*1024+n; segments flat [r][128]) ----------
struct Segs { const u16* p[12]; };
DEVI const u16* seg_sel(const Segs& s, int i) {
  switch (i) {
    case 0: return s.p[0]; case 1: return s.p[1]; case 2: return s.p[2];
    case 3: return s.p[3]; case 4: return s.p[4]; case 5: return s.p[5];
    case 6: return s.p[6]; case 7: return s.p[7]; case 8: return s.p[8];
    case 9: return s.p[9]; case 10: return s.p[10]; default: return s.p[11];
  }
}

template<int EPI>   // 0 = GATE (sigmoid -> r*h split N+T, u bf16), 1 = CAND (tanh -> hnew)
__global__ __launch_bounds__(256) void gemm_wseg(
    Segs segs, const u16* __restrict__ WT, int Ktot,
    const float* __restrict__ bias, const float* __restrict__ Hprev,
    const u16* __restrict__ xadd,
    u16* __restrict__ rh_hi, u16* __restrict__ rh_lo, u16* __restrict__ rh_t,
    u16* __restrict__ usig,
    float* __restrict__ hnew_out, u16* __restrict__ xa_hi, u16* __restrict__ xa_lo,
    u16* __restrict__ xa_t)
{
  __shared__ char smem[49152];
  const int tid = threadIdx.x, wid = tid >> 6, lane = tid & 63;
  const int wr = wid >> 1, wc = wid & 1, l15 = lane & 15, l4 = lane >> 4;
  const int otile = blockIdx.x * 128, rtile = blockIdx.y * 128;
  char* A0 = smem;          char* A1 = smem + 8192;  char* A2 = smem + 16384;
  char* B0 = smem + 24576;  char* B1 = smem + 32768; char* B2 = smem + 40960;
  const int s_row = lane >> 2, s_kcp = lane & 3;

  f32x4 acc[4][4];
#pragma unroll
  for (int i = 0; i < 4; i++)
#pragma unroll
    for (int j = 0; j < 4; j++) acc[i][j] = (f32x4){0.f, 0.f, 0.f, 0.f};

  const int NKS = Ktot >> 5;
  auto stage = [&](char* Ab, char* Bb, int ks) {
    const int k0 = ks * 32;
    const int sidx = ks >> 2, si0 = (ks & 3) * 32;
    const u16* sp = seg_sel(segs, sidx);
#pragma unroll
    for (int c = 0; c < 2; c++) {
      const int bb = wid * 2 + c;
      const int arow = bb * 16 + s_row;
      gl_lds16(WT + (long)(otile + arow) * Ktot + k0 + ((s_kcp ^ (arow & 3)) * 8), Ab + bb * 1024);
      const int r = rtile + bb * 16 + s_row;
      gl_lds16(sp + (long)r * 128 + si0 + ((s_kcp ^ (r & 3)) * 8), Bb + bb * 1024);
    }
  };
  auto compute = [&](char* Ab, char* Bb) {
    bf16x8 af[4], bfr[4];
#pragma unroll
    for (int mb = 0; mb < 4; mb++) {
      const int row = wr * 64 + mb * 16 + l15;
      af[mb] = *(const bf16x8*)(Ab + row * 64 + ((l4 ^ (row & 3)) * 16));
    }
#pragma unroll
    for (int nb = 0; nb < 4; nb++) {
      const int row = wc * 64 + nb * 16 + l15;
      bfr[nb] = *(const bf16x8*)(Bb + row * 64 + ((l4 ^ (row & 3)) * 16));
    }
#pragma unroll
    for (int mb = 0; mb < 4; mb++)
#pragma unroll
      for (int nb = 0; nb < 4; nb++)
        acc[mb][nb] = mfma16(af[mb], bfr[nb], acc[mb][nb]);
  };

  stage(A0, B0, 0);
  stage(A1, B1, 1);
  char* cA = A0; char* cB = B0;
  char* mA = A1; char* mB = B1;
  char* fA = A2; char* fB = B2;
  for (int ks = 0; ks + 2 < NKS; ks++) {
    stage(fA, fB, ks + 2);
    asm volatile("s_waitcnt vmcnt(8)" ::: "memory");
    __builtin_amdgcn_s_barrier();
    __builtin_amdgcn_sched_barrier(0);
    compute(cA, cB);
    asm volatile("" ::: "memory");
    __builtin_amdgcn_s_barrier();
    __builtin_amdgcn_sched_barrier(0);
    char* t = cA; cA = mA; mA = fA; fA = t;
    t = cB; cB = mB; mB = fB; fB = t;
  }
  asm volatile("s_waitcnt vmcnt(4)" ::: "memory");
  __builtin_amdgcn_s_barrier();
  __builtin_amdgcn_sched_barrier(0);
  compute(cA, cB);
  asm volatile("s_waitcnt vmcnt(0)" ::: "memory");
  __builtin_amdgcn_s_barrier();
  __builtin_amdgcn_sched_barrier(0);
  compute(mA, mB);

#pragma unroll
  for (int mb = 0; mb < 4; mb++) {
#pragma unroll
    for (int nb = 0; nb < 4; nb++) {
      const int o = otile + wr * 64 + mb * 16 + l4 * 4;
      const int rr = rtile + wc * 64 + nb * 16 + l15;
      const int n = rr & 1023, b = rr >> 10;
      f32x4 v = acc[mb][nb];
      float4 bv = *(const float4*)(bias + o);
      float a0 = 0.f, a1 = 0.f, a2 = 0.f, a3 = 0.f;
      if (xadd != nullptr) {
        const int xs = (EPI == 0) ? 256 : 128;
        u32x2 xv = *(const u32x2*)(xadd + (long)rr * xs + o);
        a0 = bf2f((u16)(xv[0] & 0xffffu)); a1 = bf2f((u16)(xv[0] >> 16));
        a2 = bf2f((u16)(xv[1] & 0xffffu)); a3 = bf2f((u16)(xv[1] >> 16));
      }
      if (EPI == 0) {
        float s0 = sigm(v[0] + bv.x + a0), s1 = sigm(v[1] + bv.y + a1);
        float s2 = sigm(v[2] + bv.z + a2), s3 = sigm(v[3] + bv.w + a3);
        if (o < 128) {
          float4 hv = *(const float4*)(Hprev + (long)rr * 128 + o);
          float r0 = s0 * hv.x, r1 = s1 * hv.y, r2 = s2 * hv.z, r3 = s3 * hv.w;
          u16 h0 = f2bf(r0), h1 = f2bf(r1), h2 = f2bf(r2), h3 = f2bf(r3);
          long d = (long)rr * 128 + o;
          u32x2 wh; wh[0] = (u32)h0 | ((u32)h1 << 16); wh[1] = (u32)h2 | ((u32)h3 << 16);
          *(u32x2*)(rh_hi + d) = wh;
          u32x2 wl; wl[0] = pk2bf(r0 - bf2f(h0), r1 - bf2f(h1));
          wl[1] = pk2bf(r2 - bf2f(h2), r3 - bf2f(h3));
          *(u32x2*)(rh_lo + d) = wl;
          u16* rt = rh_t + (long)(b * 128 + o) * 1024 + n;
          rt[0] = h0; rt[1024] = h1; rt[2048] = h2; rt[3072] = h3;
        } else {
          u32x2 wu; wu[0] = pk2bf(s0, s1); wu[1] = pk2bf(s2, s3);
          *(u32x2*)(usig + (long)rr * 128 + (o - 128)) = wu;
        }
      } else {
        float c0 = tanh_(v[0] + bv.x + a0), c1 = tanh_(v[1] + bv.y + a1);
        float c2 = tanh_(v[2] + bv.z + a2), c3 = tanh_(v[3] + bv.w + a3);
        u32x2 uv = *(const u32x2*)(usig + (long)rr * 128 + o);
        float u0 = bf2f((u16)(uv[0] & 0xffffu)), u1 = bf2f((u16)(uv[0] >> 16));
        float u2 = bf2f((u16)(uv[1] & 0xffffu)), u3 = bf2f((u16)(uv[1] >> 16));
        float4 hv = *(const float4*)(Hprev + (long)rr * 128 + o);
        float h0n = u0 * hv.x + (1.f - u0) * c0;
        float h1n = u1 * hv.y + (1.f - u1) * c1;
        float h2n = u2 * hv.z + (1.f - u2) * c2;
        float h3n = u3 * hv.w + (1.f - u3) * c3;
        *(float4*)(hnew_out + (long)rr * 128 + o) = make_float4(h0n, h1n, h2n, h3n);
        if (xa_hi != nullptr) {
          u16 x0 = f2bf(h0n), x1 = f2bf(h1n), x2 = f2bf(h2n), x3 = f2bf(h3n);
          long d = (long)rr * 128 + o;
          u32x2 wh; wh[0] = (u32)x0 | ((u32)x1 << 16); wh[1] = (u32)x2 | ((u32)x3 << 16);
          *(u32x2*)(xa_hi + d) = wh;
          u32x2 wl; wl[0] = pk2bf(h0n - bf2f(x0), h1n - bf2f(x1));
          wl[1] = pk2bf(h2n - bf2f(x2), h3n - bf2f(x3));
          *(u32x2*)(xa_lo + d) = wl;
          u16* xt = xa_t + (long)(b * 128 + o) * 1024 + n;
          xt[0] = x0; xt[1024] = x1; xt[2048] = x2; xt[3072] = x3;
        }
      }
    }
  }
}

// ---------- projection ----------
__global__ __launch_bounds__(256) void proj_k(const float* __restrict__ h1n, const float* __restrict__ pw,
                                              const float* __restrict__ pb, float* __restrict__ out) {
  int wid = threadIdx.x >> 6, lane = threadIdx.x & 63;
  int r = blockIdx.x * 4 + wid;
  int b = r >> 10, n = r & 1023;
  const float* hp = h1n + (long)b * 131072 + n * 128;
  float ha = hp[lane], hb = hp[lane + 64];
  float p0 = ha * pw[lane * 2]     + hb * pw[(lane + 64) * 2];
  float p1 = ha * pw[lane * 2 + 1] + hb * pw[(lane + 64) * 2 + 1];
  for (int off = 32; off; off >>= 1) { p0 += __shfl_down(p0, off); p1 += __shfl_down(p1, off); }
  if (!lane) {
    out[(long)b * 2048 + n * 2]     = p0 + pb[0];
    out[(long)b * 2048 + n * 2 + 1] = p1 + pb[1];
  }
}

// ---------- host ----------
extern "C" void kernel_launch(void* const* d_in, const int* in_sizes, int n_in,
                              void* d_out, int out_size, void* d_ws, size_t ws_size,
                              hipStream_t stream) {
  (void)in_sizes; (void)n_in; (void)out_size; (void)ws_size;
  const float* inputs = (const float*)d_in[0];
  const float* hidden = (const float*)d_in[1];
  const float* adj    = (const float*)d_in[2];
  const float* gw0 = (const float*)d_in[3];
  const float* gb0 = (const float*)d_in[4];
  const float* cw0 = (const float*)d_in[5];
  const float* cb0 = (const float*)d_in[6];
  const float* gw1 = (const float*)d_in[7];
  const float* gb1 = (const float*)d_in[8];
  const float* cw1 = (const float*)d_in[9];
  const float* cb1 = (const float*)d_in[10];
  const float* pw  = (const float*)d_in[11];
  const float* pb  = (const float*)d_in[12];

  float* out    = (float*)d_out;
  float* out_h0 = out + 131072;
  float* out_h1 = out_h0 + 8388608;
  const float* h0 = hidden;
  const float* h1 = hidden + 8388608;

  u16* OH1a = (u16*)out_h1;            // h1 hiN
  u16* OH1b = OH1a + 8388608;          // h1 loN

  char* wp = (char*)d_ws;
  auto alloc = [&](size_t bytes) { char* r = wp; wp += (bytes + 255) & ~(size_t)255; return r; };
  u16*   S0b  = (u16*)  alloc(1048576 * 2);
  u16*   S1b  = (u16*)  alloc(1048576 * 2);
  float* rs   = (float*)alloc(1024 * 4);
  float* cs   = (float*)alloc(1024 * 4);
  u16*   WG0  = (u16*)  alloc((size_t)256 * 768 * 2);
  u16*   WC0  = (u16*)  alloc((size_t)128 * 768 * 2);
  u16*   WG1  = (u16*)  alloc((size_t)256 * 1536 * 2);
  u16*   WC1  = (u16*)  alloc((size_t)128 * 1536 * 2);
  u16*   Bb   = (u16*)  alloc((size_t)13 * 8388608 * 2);   // 13 chain slots
  u16*   USIG = (u16*)  alloc((size_t)8388608 * 2);
  float* XCH  = (float*)alloc((size_t)5 * 131072 * 4);
  auto BB = [&](int i) { return Bb + (size_t)i * 8388608; };
  auto XC = [&](int i) { return XCH + (size_t)i * 131072; };
  u16* XGg = BB(4);   // spans slots 4,5
  u16* XGc = BB(6);

  // prep
  sums_k<<<1040, 256, 0, stream>>>(adj, rs, cs);
  s0_build<<<dim3(32, 32), 256, 0, stream>>>(adj, rs, S0b);
  s1_build<<<4096, 256, 0, stream>>>(adj, cs, S1b);
  pack_w<<<768,  256, 0, stream>>>(gw0, WG0, 256, 768, 2, 0);
  pack_w<<<384,  256, 0, stream>>>(cw0, WC0, 128, 768, 2, 0);
  pack_w<<<1536, 256, 0, stream>>>(gw1, WG1, 256, 1536, 0, 128);
  pack_w<<<768,  256, 0, stream>>>(cw1, WC1, 128, 1536, 0, 128);
  build_hx<<<dim3(32, 4, 64), 256, 0, stream>>>(h0, BB(0), BB(1), BB(2));      // A,B + x0T->C
  build_hx<<<dim3(32, 4, 64), 256, 0, stream>>>(h1, OH1a, OH1b, BB(3));        // h1T->D

  // x-part exact chains + additive preacts
  xch0_build<<<512, 256, 0, stream>>>(inputs, XC(0));
  xch_diffuse<<<1024, 128, 0, stream>>>(S0b, XC(0), XC(1));
  xch_cheb   <<<1024, 128, 0, stream>>>(S0b, XC(1), XC(0), XC(2));
  xch_diffuse<<<1024, 128, 0, stream>>>(S1b, XC(0), XC(3));
  xch_cheb   <<<1024, 128, 0, stream>>>(S1b, XC(3), XC(0), XC(4));
  xg_build<<<65536, 256, 0, stream>>>(gw0, cw0, XCH, XGg, XGc);

  DiffJobs dj{};
  // L0 s-chain: {s1: S0*x0T -> H(+T I) ; s3: S1*x0T -> J(+T K)}
  dj.j[0] = {BB(2), S0b, BB(7), BB(8)};
  dj.j[1] = {BB(2), S1b, BB(9), BB(10)};
  gemm_diffz<<<dim3(64, 8, 2), 256, 0, stream>>>(dj);
  // {s2: S0*s1T -> L ; s4: S1*s3T -> M}
  dj.j[0] = {BB(8),  S0b, BB(11), nullptr};
  dj.j[1] = {BB(10), S1b, BB(12), nullptr};
  gemm_diffz<<<dim3(64, 8, 2), 256, 0, stream>>>(dj);

  // GATE0: segs {A,B,H,L,J,M}; rhN->C, rhlo->K, rhT->I
  Segs sg0{};
  sg0.p[0] = BB(0); sg0.p[1] = BB(1); sg0.p[2] = BB(7); sg0.p[3] = BB(11); sg0.p[4] = BB(9); sg0.p[5] = BB(12);
  gemm_wseg<0><<<dim3(2, 512), 256, 0, stream>>>(sg0, WG0, 768, gb0, h0, XGg,
      BB(2), BB(10), BB(8), USIG, nullptr, nullptr, nullptr, nullptr);

  // L0 c-chain: {c1: S0*rhT -> E(+T F) ; c3: S1*rhT -> A(+T B)}
  dj.j[0] = {BB(8), S0b, BB(4), BB(5)};
  dj.j[1] = {BB(8), S1b, BB(0), BB(1)};
  gemm_diffz<<<dim3(64, 8, 2), 256, 0, stream>>>(dj);
  // {c2: S0*c1T -> H ; c4: S1*c3T -> J}
  dj.j[0] = {BB(5), S0b, BB(7), nullptr};
  dj.j[1] = {BB(1), S1b, BB(9), nullptr};
  gemm_diffz<<<dim3(64, 8, 2), 256, 0, stream>>>(dj);

  // CAND0: segs {C,K,E,H,A,J}; xadd=XGc; out_h0; xaN->L, xalo->M, xaT->B
  Segs sc0{};
  sc0.p[0] = BB(2); sc0.p[1] = BB(10); sc0.p[2] = BB(4); sc0.p[3] = BB(7); sc0.p[4] = BB(0); sc0.p[5] = BB(9);
  gemm_wseg<1><<<dim3(1, 512), 256, 0, stream>>>(sc0, WC0, 768, cb0, h0, XGc,
      nullptr, nullptr, nullptr, USIG, out_h0, BB(11), BB(12), BB(1));

  // L1 wave-1 (z=4): {s1': S0*xaT -> A(+T C) ; s3': S1*xaT -> E(+T F) ; t1: S0*h1T -> I(+T G) ; t3: S1*h1T -> J(+T H)}
  dj.j[0] = {BB(1), S0b, BB(0), BB(2)};
  dj.j[1] = {BB(1), S1b, BB(4), BB(5)};
  dj.j[2] = {BB(3), S0b, BB(8), BB(6)};
  dj.j[3] = {BB(3), S1b, BB(9), BB(7)};
  gemm_diffz<<<dim3(64, 8, 4), 256, 0, stream>>>(dj);
  // {s2': S0*s1'T -> K ; s4': S1*s3'T -> D}
  dj.j[0] = {BB(2), S0b, BB(10), nullptr};
  dj.j[1] = {BB(5), S1b, BB(3),  nullptr};
  gemm_diffz<<<dim3(64, 8, 2), 256, 0, stream>>>(dj);
  // {t2: S0*t1T -> B ; t4: S1*t3T -> C}
  dj.j[0] = {BB(6), S0b, BB(1), nullptr};
  dj.j[1] = {BB(7), S1b, BB(2), nullptr};
  gemm_diffz<<<dim3(64, 8, 2), 256, 0, stream>>>(dj);

  // GATE1: segs x{L,M,A,K,E,D} h{OH1a,OH1b,I,B,J,C}; rh1N->F, rh1lo->H, rh1T->G
  Segs sg1{};
  sg1.p[0] = BB(11); sg1.p[1] = BB(12); sg1.p[2] = BB(0); sg1.p[3] = BB(10); sg1.p[4] = BB(4); sg1.p[5] = BB(3);
  sg1.p[6] = OH1a;   sg1.p[7] = OH1b;   sg1.p[8] = BB(8); sg1.p[9] = BB(1);  sg1.p[10] = BB(9); sg1.p[11] = BB(2);
  gemm_wseg<0><<<dim3(2, 512), 256, 0, stream>>>(sg1, WG1, 1536, gb1, h1, nullptr,
      BB(5), BB(7), BB(6), USIG, nullptr, nullptr, nullptr, nullptr);

  // L1 d-chain: {d1: S0*rh1T -> I(+T B) ; d3: S1*rh1T -> J(+T C)}
  dj.j[0] = {BB(6), S0b, BB(8), BB(1)};
  dj.j[1] = {BB(6), S1b, BB(9), BB(2)};
  gemm_diffz<<<dim3(64, 8, 2), 256, 0, stream>>>(dj);
  // d2: S0*d1T -> G
  dj.j[0] = {BB(1), S0b, BB(6), nullptr};
  gemm_diffz<<<dim3(64, 8, 1), 256, 0, stream>>>(dj);
  // d4: S1*d3T -> B
  dj.j[0] = {BB(2), S1b, BB(1), nullptr};
  gemm_diffz<<<dim3(64, 8, 1), 256, 0, stream>>>(dj);

  // CAND1: segs x{L,M,A,K,E,D} rh{F,H,I,G,J,B}; Hprev=h1 -> out_h1
  Segs sc1{};
  sc1.p[0] = BB(11); sc1.p[1] = BB(12); sc1.p[2] = BB(0); sc1.p[3] = BB(10); sc1.p[4] = BB(4); sc1.p[5] = BB(3);
  sc1.p[6] = BB(5);  sc1.p[7] = BB(7);  sc1.p[8] = BB(8); sc1.p[9] = BB(6);  sc1.p[10] = BB(9); sc1.p[11] = BB(1);
  gemm_wseg<1><<<dim3(1, 512), 256, 0, stream>>>(sc1, WC1, 1536, cb1, h1, nullptr,
      nullptr, nullptr, nullptr, USIG, out_h1, nullptr, nullptr, nullptr);

  // projection
  proj_k<<<16384, 256, 0, stream>>>(out_h1, pw, pb, out);
}

// Round 8
// 1167.333 us; speedup vs baseline: 1.5430x; 1.0106x over previous
//
#include <hip/hip_runtime.h>
#include <hip/hip_bf16.h>

typedef unsigned short u16;
typedef unsigned int u32;
typedef __attribute__((ext_vector_type(2))) unsigned int u32x2;
typedef __attribute__((ext_vector_type(4))) float f32x4;
typedef __attribute__((ext_vector_type(8))) __bf16 bf16x8;

#define DEVI static __device__ __forceinline__

// ---------- scalar helpers ----------
DEVI u16 f2bf(float x) {
  union { float f; u32 u; } v; v.f = x;
  u32 r = v.u + 0x7fffu + ((v.u >> 16) & 1u);
  return (u16)(r >> 16);
}
DEVI float bf2f(u16 h) { union { u32 u; float f; } v; v.u = ((u32)h) << 16; return v.f; }
DEVI u32 pk2bf(float a, float b) { return (u32)f2bf(a) | ((u32)f2bf(b) << 16); }
DEVI float sigm(float x) { return 1.f / (1.f + __expf(-x)); }
DEVI float tanh_(float x) {
  float a = fabsf(x);
  float e = __expf(-2.f * a);
  float t = (1.f - e) / (1.f + e);
  return copysignf(t, x);
}

DEVI void gl_lds16(const u16* g, void* l) {
  __builtin_amdgcn_global_load_lds(
      (const __attribute__((address_space(1))) u32*)(const void*)g,
      (__attribute__((address_space(3))) u32*)l, 16, 0, 0);
}
DEVI f32x4 mfma16(bf16x8 a, bf16x8 b, f32x4 c) {
  return __builtin_amdgcn_mfma_f32_16x16x32_bf16(a, b, c, 0, 0, 0);
}

// 64B-row LDS swizzle key: bank alignment repeats every 2 rows -> key on (row>>1)&3.
#define SWZ(row) (((row) >> 1) & 3)

// ---------- prep kernels ----------
__global__ void sums_k(const float* __restrict__ adj, float* __restrict__ rs, float* __restrict__ cs) {
  __shared__ float red[256];
  int bid = blockIdx.x, tid = threadIdx.x;
  if (bid < 1024) {
    float a = 0.f;
    for (int j = tid; j < 1024; j += 256) a += adj[bid * 1024 + j];
    red[tid] = a; __syncthreads();
    for (int s = 128; s; s >>= 1) { if (tid < s) red[tid] += red[tid + s]; __syncthreads(); }
    if (!tid) rs[bid] = red[0];
  } else {
    int c0 = (bid - 1024) * 64;
    int c = tid & 63, r0 = tid >> 6;
    float a = 0.f;
    for (int r = r0; r < 1024; r += 4) a += adj[r * 1024 + c0 + c];
    red[tid] = a; __syncthreads();
    if (tid < 64) cs[c0 + c] = red[c] + red[64 + c] + red[128 + c] + red[192 + c];
  }
}

__global__ void s0_build(const float* __restrict__ adj, const float* __restrict__ rs, u16* __restrict__ S0) {
  __shared__ float tile[32][33];
  int i0 = blockIdx.x * 32, j0 = blockIdx.y * 32;
  int tx = threadIdx.x & 31, ty = threadIdx.x >> 5;
  for (int yy = ty; yy < 32; yy += 8)
    tile[yy][tx] = adj[(j0 + yy) * 1024 + i0 + tx];
  __syncthreads();
  for (int yy = ty; yy < 32; yy += 8)
    S0[(i0 + yy) * 1024 + j0 + tx] = f2bf(tile[tx][yy] / rs[j0 + tx]);
}

__global__ void s1_build(const float* __restrict__ adj, const float* __restrict__ cs, u16* __restrict__ S1) {
  int idx = blockIdx.x * 256 + threadIdx.x;
  int j = idx & 1023;
  S1[idx] = f2bf(adj[idx] / cs[j]);
}

// pack h-part weights with cheb-elimination fold; pure full segments.
__global__ void pack_w(const float* __restrict__ src, u16* __restrict__ dst,
                       int NO, int Ktot, int off0, int off1) {
  int idx = blockIdx.x * 256 + threadIdx.x;
  if (idx >= NO * Ktot) return;
  int o = idx / Ktot, k = idx % Ktot;
  int seg = k >> 7, i = k & 127;
  int mo = seg % 6;
  int pos = ((seg / 6) ? off1 : off0) + i;
  const float* wr = src + (long)pos * 5 * NO + o;
  float v;
  switch (mo) {
    case 0: case 1: v = wr[0] - wr[(long)2 * NO] - wr[(long)4 * NO]; break;
    case 2: v = wr[(long)1 * NO]; break;
    case 3: v = 2.f * wr[(long)2 * NO]; break;
    case 4: v = wr[(long)3 * NO]; break;
    default: v = 2.f * wr[(long)4 * NO]; break;
  }
  dst[idx] = f2bf(v);
}

// h (B, N*128) fp32 -> hiN/loN flat [r=b*1024+n][u] bf16 + hiT [b*128+u][n]
__global__ void build_hx(const float* __restrict__ src, u16* __restrict__ hiN,
                         u16* __restrict__ loN, u16* __restrict__ hiT) {
  __shared__ u16 t[32][33];
  int n0 = blockIdx.x * 32, u0 = blockIdx.y * 32, b = blockIdx.z;
  int tx = threadIdx.x & 31, ty = threadIdx.x >> 5;
  for (int yy = ty; yy < 32; yy += 8) {
    long d = (long)b * 131072 + (n0 + yy) * 128 + u0 + tx;
    float v = src[d];
    u16 h = f2bf(v);
    hiN[d] = h;
    loN[d] = f2bf(v - bf2f(h));
    t[yy][tx] = h;
  }
  __syncthreads();
  for (int yy = ty; yy < 32; yy += 8)
    hiT[(long)(b * 128 + u0 + yy) * 1024 + n0 + tx] = t[tx][yy];
}

// ---------- x-part (layer 0): exact fp32 path ----------
__global__ void xch0_build(const float* __restrict__ inp, float* __restrict__ x0) {
  int idx = blockIdx.x * 256 + threadIdx.x;   // 131072
  int n = idx >> 7, c = idx & 127, b = c >> 1, d = c & 1;
  x0[idx] = inp[b * 2048 + n * 2 + d];
}

__global__ void xch_diffuse(const u16* __restrict__ S, const float* __restrict__ xin,
                            float* __restrict__ xout) {
  int n = blockIdx.x, c = threadIdx.x;
  float acc = 0.f;
  for (int k = 0; k < 1024; k++) acc += bf2f(S[n * 1024 + k]) * xin[k * 128 + c];
  xout[n * 128 + c] = acc;
}

__global__ void xch_cheb(const u16* __restrict__ S, const float* __restrict__ xin,
                         const float* __restrict__ x0, float* __restrict__ xout) {
  int n = blockIdx.x, c = threadIdx.x;
  float acc = 0.f;
  for (int k = 0; k < 1024; k++) acc += bf2f(S[n * 1024 + k]) * xin[k * 128 + c];
  xout[n * 128 + c] = 2.f * acc - x0[n * 128 + c];
}

// XG[r][o] with r = b*1024 + n
__global__ void xg_build(const float* __restrict__ gw0, const float* __restrict__ cw0,
                         const float* __restrict__ xch,
                         u16* __restrict__ xgg, u16* __restrict__ xgc) {
  int r = blockIdx.x;           // 65536
  int n = r & 1023, b = r >> 10;
  int t = threadIdx.x;          // 256
  __shared__ float xv[10];
  if (t < 10) { int m = t % 5, p = t / 5; xv[t] = xch[(long)m * 131072 + n * 128 + b * 2 + p]; }
  __syncthreads();
  float a = 0.f;
#pragma unroll
  for (int q = 0; q < 10; q++) { int m = q % 5, p = q / 5;
    a += gw0[(long)(p * 5 + m) * 256 + t] * xv[q]; }
  xgg[(long)r * 256 + t] = f2bf(a);
  if (t < 128) {
    float a2 = 0.f;
#pragma unroll
    for (int q = 0; q < 10; q++) { int m = q % 5, p = q / 5;
      a2 += cw0[(long)(p * 5 + m) * 128 + t] * xv[q]; }
    xgc[(long)r * 128 + t] = f2bf(a2);
  }
}

// ---------- fused diffusion GEMM:  Y[n][f] = sum_k S[n][k] * fT[f][k] ----------
// Triple-buffered counted-vmcnt pipeline.
struct DiffJob { const u16* X; const u16* S; u16* YN; u16* YT; };
struct DiffJobs { DiffJob j[4]; };

__global__ __launch_bounds__(256) void gemm_diffz(DiffJobs jobs) {
  DiffJob J = jobs.j[blockIdx.z];
  __shared__ char smem[49152];
  const int tid = threadIdx.x, wid = tid >> 6, lane = tid & 63;
  const int wr = wid >> 1, wc = wid & 1, l15 = lane & 15, l4 = lane >> 4;
  const int ntile = blockIdx.y * 128;
  const int fbase = blockIdx.x * 128;
  char* A0 = smem;          char* A1 = smem + 8192;  char* A2 = smem + 16384;
  char* B0 = smem + 24576;  char* B1 = smem + 32768; char* B2 = smem + 40960;
  const int s_row = lane >> 2, s_kcp = lane & 3;

  f32x4 acc[4][4];
#pragma unroll
  for (int i = 0; i < 4; i++)
#pragma unroll
    for (int j = 0; j < 4; j++) acc[i][j] = (f32x4){0.f, 0.f, 0.f, 0.f};

  auto stage = [&](char* Ab, char* Bb, int ks) {
    const int k0 = ks * 32;
#pragma unroll
    for (int c = 0; c < 2; c++) {
      const int bb = wid * 2 + c;
      const int row = bb * 16 + s_row;
      const int sw = (s_kcp ^ SWZ(row)) * 8;
      gl_lds16(J.S + (long)(ntile + row) * 1024 + k0 + sw, Ab + bb * 1024);
      gl_lds16(J.X + (long)(fbase + row) * 1024 + k0 + sw, Bb + bb * 1024);
    }
  };
  auto compute = [&](char* Ab, char* Bb) {
    bf16x8 af[4], bfr[4];
#pragma unroll
    for (int mb = 0; mb < 4; mb++) {
      const int row = wr * 64 + mb * 16 + l15;
      af[mb] = *(const bf16x8*)(Ab + row * 64 + ((l4 ^ SWZ(row)) * 16));
    }
#pragma unroll
    for (int nb = 0; nb < 4; nb++) {
      const int row = wc * 64 + nb * 16 + l15;
      bfr[nb] = *(const bf16x8*)(Bb + row * 64 + ((l4 ^ SWZ(row)) * 16));
    }
#pragma unroll
    for (int mb = 0; mb < 4; mb++)
#pragma unroll
      for (int nb = 0; nb < 4; nb++)
        acc[mb][nb] = mfma16(af[mb], bfr[nb], acc[mb][nb]);
  };

  const int NKS = 32;
  stage(A0, B0, 0);
  stage(A1, B1, 1);
  char* cA = A0; char* cB = B0;
  char* mA = A1; char* mB = B1;
  char* fA = A2; char* fB = B2;
  for (int ks = 0; ks + 2 < NKS; ks++) {
    stage(fA, fB, ks + 2);
    asm volatile("s_waitcnt vmcnt(8)" ::: "memory");
    __builtin_amdgcn_s_barrier();
    __builtin_amdgcn_sched_barrier(0);
    compute(cA, cB);
    asm volatile("" ::: "memory");
    __builtin_amdgcn_s_barrier();
    __builtin_amdgcn_sched_barrier(0);
    char* t = cA; cA = mA; mA = fA; fA = t;
    t = cB; cB = mB; mB = fB; fB = t;
  }
  asm volatile("s_waitcnt vmcnt(4)" ::: "memory");
  __builtin_amdgcn_s_barrier();
  __builtin_amdgcn_sched_barrier(0);
  compute(cA, cB);
  asm volatile("s_waitcnt vmcnt(0)" ::: "memory");
  __builtin_amdgcn_s_barrier();
  __builtin_amdgcn_sched_barrier(0);
  compute(mA, mB);

#pragma unroll
  for (int mb = 0; mb < 4; mb++) {
#pragma unroll
    for (int nb = 0; nb < 4; nb++) {
      const int n0 = ntile + wr * 64 + mb * 16 + l4 * 4;
      const int f  = fbase + wc * 64 + nb * 16 + l15;
      const int b = f >> 7, u = f & 127;
      f32x4 v = acc[mb][nb];
      u16 h0 = f2bf(v[0]), h1 = f2bf(v[1]), h2 = f2bf(v[2]), h3 = f2bf(v[3]);
      u16* yn = J.YN + (long)b * 131072 + (long)n0 * 128 + u;
      yn[0] = h0; yn[128] = h1; yn[256] = h2; yn[384] = h3;
      if (J.YT != nullptr) {
        u32x2 wv; wv[0] = (u32)h0 | ((u32)h1 << 16); wv[1] = (u32)h2 | ((u32)h3 << 16);
        *(u32x2*)(J.YT + (long)f * 1024 + n0) = wv;
      }
    }
  }
}

// ---------- W GEMM with fused epilogue (r = b*1024+n; segments flat [r][128]) ----------
struct Segs { const u16* p[12]; };
DEVI const u16* seg_sel(const Segs& s, int i) {
  switch (i) {
    case 0: return s.p[0]; case 1: return s.p[1]; case 2: return s.p[2];
    case 3: return s.p[3]; case 4: return s.p[4]; case 5: return s.p[5];
    case 6: return s.p[6]; case 7: return s.p[7]; case 8: return s.p[8];
    case 9: return s.p[9]; case 10: return s.p[10]; default: return s.p[11];
  }
}

template<int EPI>   // 0 = GATE (sigmoid -> r*h split N+T, u bf16), 1 = CAND (tanh -> hnew)
__global__ __launch_bounds__(256) void gemm_wseg(
    Segs segs, const u16* __restrict__ WT, int Ktot,
    const float* __restrict__ bias, const float* __restrict__ Hprev,
    const u16* __restrict__ xadd,
    u16* __restrict__ rh_hi, u16* __restrict__ rh_lo, u16* __restrict__ rh_t,
    u16* __restrict__ usig,
    float* __restrict__ hnew_out, u16* __restrict__ xa_hi, u16* __restrict__ xa_lo,
    u16* __restrict__ xa_t)
{
  __shared__ char smem[49152];
  const int tid = threadIdx.x, wid = tid >> 6, lane = tid & 63;
  const int wr = wid >> 1, wc = wid & 1, l15 = lane & 15, l4 = lane >> 4;
  const int otile = blockIdx.x * 128, rtile = blockIdx.y * 128;
  char* A0 = smem;          char* A1 = smem + 8192;  char* A2 = smem + 16384;
  char* B0 = smem + 24576;  char* B1 = smem + 32768; char* B2 = smem + 40960;
  const int s_row = lane >> 2, s_kcp = lane & 3;

  f32x4 acc[4][4];
#pragma unroll
  for (int i = 0; i < 4; i++)
#pragma unroll
    for (int j = 0; j < 4; j++) acc[i][j] = (f32x4){0.f, 0.f, 0.f, 0.f};

  const int NKS = Ktot >> 5;
  auto stage = [&](char* Ab, char* Bb, int ks) {
    const int k0 = ks * 32;
    const int sidx = ks >> 2, si0 = (ks & 3) * 32;
    const u16* sp = seg_sel(segs, sidx);
#pragma unroll
    for (int c = 0; c < 2; c++) {
      const int bb = wid * 2 + c;
      const int arow = bb * 16 + s_row;
      gl_lds16(WT + (long)(otile + arow) * Ktot + k0 + ((s_kcp ^ SWZ(arow)) * 8), Ab + bb * 1024);
      const int r = rtile + bb * 16 + s_row;
      gl_lds16(sp + (long)r * 128 + si0 + ((s_kcp ^ SWZ(r)) * 8), Bb + bb * 1024);
    }
  };
  auto compute = [&](char* Ab, char* Bb) {
    bf16x8 af[4], bfr[4];
#pragma unroll
    for (int mb = 0; mb < 4; mb++) {
      const int row = wr * 64 + mb * 16 + l15;
      af[mb] = *(const bf16x8*)(Ab + row * 64 + ((l4 ^ SWZ(row)) * 16));
    }
#pragma unroll
    for (int nb = 0; nb < 4; nb++) {
      const int row = wc * 64 + nb * 16 + l15;
      bfr[nb] = *(const bf16x8*)(Bb + row * 64 + ((l4 ^ SWZ(row)) * 16));
    }
#pragma unroll
    for (int mb = 0; mb < 4; mb++)
#pragma unroll
      for (int nb = 0; nb < 4; nb++)
        acc[mb][nb] = mfma16(af[mb], bfr[nb], acc[mb][nb]);
  };

  stage(A0, B0, 0);
  stage(A1, B1, 1);
  char* cA = A0; char* cB = B0;
  char* mA = A1; char* mB = B1;
  char* fA = A2; char* fB = B2;
  for (int ks = 0; ks + 2 < NKS; ks++) {
    stage(fA, fB, ks + 2);
    asm volatile("s_waitcnt vmcnt(8)" ::: "memory");
    __builtin_amdgcn_s_barrier();
    __builtin_amdgcn_sched_barrier(0);
    compute(cA, cB);
    asm volatile("" ::: "memory");
    __builtin_amdgcn_s_barrier();
    __builtin_amdgcn_sched_barrier(0);
    char* t = cA; cA = mA; mA = fA; fA = t;
    t = cB; cB = mB; mB = fB; fB = t;
  }
  asm volatile("s_waitcnt vmcnt(4)" ::: "memory");
  __builtin_amdgcn_s_barrier();
  __builtin_amdgcn_sched_barrier(0);
  compute(cA, cB);
  asm volatile("s_waitcnt vmcnt(0)" ::: "memory");
  __builtin_amdgcn_s_barrier();
  __builtin_amdgcn_sched_barrier(0);
  compute(mA, mB);

#pragma unroll
  for (int mb = 0; mb < 4; mb++) {
#pragma unroll
    for (int nb = 0; nb < 4; nb++) {
      const int o = otile + wr * 64 + mb * 16 + l4 * 4;
      const int rr = rtile + wc * 64 + nb * 16 + l15;
      const int n = rr & 1023, b = rr >> 10;
      f32x4 v = acc[mb][nb];
      float4 bv = *(const float4*)(bias + o);
      float a0 = 0.f, a1 = 0.f, a2 = 0.f, a3 = 0.f;
      if (xadd != nullptr) {
        const int xs = (EPI == 0) ? 256 : 128;
        u32x2 xv = *(const u32x2*)(xadd + (long)rr * xs + o);
        a0 = bf2f((u16)(xv[0] & 0xffffu)); a1 = bf2f((u16)(xv[0] >> 16));
        a2 = bf2f((u16)(xv[1] & 0xffffu)); a3 = bf2f((u16)(xv[1] >> 16));
      }
      if (EPI == 0) {
        float s0 = sigm(v[0] + bv.x + a0), s1 = sigm(v[1] + bv.y + a1);
        float s2 = sigm(v[2] + bv.z + a2), s3 = sigm(v[3] + bv.w + a3);
        if (o < 128) {
          float4 hv = *(const float4*)(Hprev + (long)rr * 128 + o);
          float r0 = s0 * hv.x, r1 = s1 * hv.y, r2 = s2 * hv.z, r3 = s3 * hv.w;
          u16 h0 = f2bf(r0), h1 = f2bf(r1), h2 = f2bf(r2), h3 = f2bf(r3);
          long d = (long)rr * 128 + o;
          u32x2 wh; wh[0] = (u32)h0 | ((u32)h1 << 16); wh[1] = (u32)h2 | ((u32)h3 << 16);
          *(u32x2*)(rh_hi + d) = wh;
          u32x2 wl; wl[0] = pk2bf(r0 - bf2f(h0), r1 - bf2f(h1));
          wl[1] = pk2bf(r2 - bf2f(h2), r3 - bf2f(h3));
          *(u32x2*)(rh_lo + d) = wl;
          u16* rt = rh_t + (long)(b * 128 + o) * 1024 + n;
          rt[0] = h0; rt[1024] = h1; rt[2048] = h2; rt[3072] = h3;
        } else {
          u32x2 wu; wu[0] = pk2bf(s0, s1); wu[1] = pk2bf(s2, s3);
          *(u32x2*)(usig + (long)rr * 128 + (o - 128)) = wu;
        }
      } else {
        float c0 = tanh_(v[0] + bv.x + a0), c1 = tanh_(v[1] + bv.y + a1);
        float c2 = tanh_(v[2] + bv.z + a2), c3 = tanh_(v[3] + bv.w + a3);
        u32x2 uv = *(const u32x2*)(usig + (long)rr * 128 + o);
        float u0 = bf2f((u16)(uv[0] & 0xffffu)), u1 = bf2f((u16)(uv[0] >> 16));
        float u2 = bf2f((u16)(uv[1] & 0xffffu)), u3 = bf2f((u16)(uv[1] >> 16));
        float4 hv = *(const float4*)(Hprev + (long)rr * 128 + o);
        float h0n = u0 * hv.x + (1.f - u0) * c0;
        float h1n = u1 * hv.y + (1.f - u1) * c1;
        float h2n = u2 * hv.z + (1.f - u2) * c2;
        float h3n = u3 * hv.w + (1.f - u3) * c3;
        *(float4*)(hnew_out + (long)rr * 128 + o) = make_float4(h0n, h1n, h2n, h3n);
        if (xa_hi != nullptr) {
          u16 x0 = f2bf(h0n), x1 = f2bf(h1n), x2 = f2bf(h2n), x3 = f2bf(h3n);
          long d = (long)rr * 128 + o;
          u32x2 wh; wh[0] = (u32)x0 | ((u32)x1 << 16); wh[1] = (u32)x2 | ((u32)x3 << 16);
          *(u32x2*)(xa_hi + d) = wh;
          u32x2 wl; wl[0] = pk2bf(h0n - bf2f(x0), h1n - bf2f(x1));
          wl[1] = pk2bf(h2n - bf2f(x2), h3n - bf2f(x3));
          *(u32x2*)(xa_lo + d) = wl;
          u16* xt = xa_t + (long)(b * 128 + o) * 1024 + n;
          xt[0] = x0; xt[1024] = x1; xt[2048] = x2; xt[3072] = x3;
        }
      }
    }
  }
}

// ---------- projection ----------
__global__ __launch_bounds__(256) void proj_k(const float* __restrict__ h1n, const float* __restrict__ pw,
                                              const float* __restrict__ pb, float* __restrict__ out) {
  int wid = threadIdx.x >> 6, lane = threadIdx.x & 63;
  int r = blockIdx.x * 4 + wid;
  int b = r >> 10, n = r & 1023;
  const float* hp = h1n + (long)b * 131072 + n * 128;
  float ha = hp[lane], hb = hp[lane + 64];
  float p0 = ha * pw[lane * 2]     + hb * pw[(lane + 64) * 2];
  float p1 = ha * pw[lane * 2 + 1] + hb * pw[(lane + 64) * 2 + 1];
  for (int off = 32; off; off >>= 1) { p0 += __shfl_down(p0, off); p1 += __shfl_down(p1, off); }
  if (!lane) {
    out[(long)b * 2048 + n * 2]     = p0 + pb[0];
    out[(long)b * 2048 + n * 2 + 1] = p1 + pb[1];
  }
}

// ---------- host ----------
extern "C" void kernel_launch(void* const* d_in, const int* in_sizes, int n_in,
                              void* d_out, int out_size, void* d_ws, size_t ws_size,
                              hipStream_t stream) {
  (void)in_sizes; (void)n_in; (void)out_size; (void)ws_size;
  const float* inputs = (const float*)d_in[0];
  const float* hidden = (const float*)d_in[1];
  const float* adj    = (const float*)d_in[2];
  const float* gw0 = (const float*)d_in[3];
  const float* gb0 = (const float*)d_in[4];
  const float* cw0 = (const float*)d_in[5];
  const float* cb0 = (const float*)d_in[6];
  const float* gw1 = (const float*)d_in[7];
  const float* gb1 = (const float*)d_in[8];
  const float* cw1 = (const float*)d_in[9];
  const float* cb1 = (const float*)d_in[10];
  const float* pw  = (const float*)d_in[11];
  const float* pb  = (const float*)d_in[12];

  float* out    = (float*)d_out;
  float* out_h0 = out + 131072;
  float* out_h1 = out_h0 + 8388608;
  const float* h0 = hidden;
  const float* h1 = hidden + 8388608;

  u16* OH1a = (u16*)out_h1;            // h1 hiN
  u16* OH1b = OH1a + 8388608;          // h1 loN

  char* wp = (char*)d_ws;
  auto alloc = [&](size_t bytes) { char* r = wp; wp += (bytes + 255) & ~(size_t)255; return r; };
  u16*   S0b  = (u16*)  alloc(1048576 * 2);
  u16*   S1b  = (u16*)  alloc(1048576 * 2);
  float* rs   = (float*)alloc(1024 * 4);
  float* cs   = (float*)alloc(1024 * 4);
  u16*   WG0  = (u16*)  alloc((size_t)256 * 768 * 2);
  u16*   WC0  = (u16*)  alloc((size_t)128 * 768 * 2);
  u16*   WG1  = (u16*)  alloc((size_t)256 * 1536 * 2);
  u16*   WC1  = (u16*)  alloc((size_t)128 * 1536 * 2);
  u16*   Bb   = (u16*)  alloc((size_t)13 * 8388608 * 2);   // 13 chain slots
  u16*   USIG = (u16*)  alloc((size_t)8388608 * 2);
  float* XCH  = (float*)alloc((size_t)5 * 131072 * 4);
  auto BB = [&](int i) { return Bb + (size_t)i * 8388608; };
  auto XC = [&](int i) { return XCH + (size_t)i * 131072; };
  u16* XGg = BB(4);   // spans slots 4,5
  u16* XGc = BB(6);

  // prep
  sums_k<<<1040, 256, 0, stream>>>(adj, rs, cs);
  s0_build<<<dim3(32, 32), 256, 0, stream>>>(adj, rs, S0b);
  s1_build<<<4096, 256, 0, stream>>>(adj, cs, S1b);
  pack_w<<<768,  256, 0, stream>>>(gw0, WG0, 256, 768, 2, 0);
  pack_w<<<384,  256, 0, stream>>>(cw0, WC0, 128, 768, 2, 0);
  pack_w<<<1536, 256, 0, stream>>>(gw1, WG1, 256, 1536, 0, 128);
  pack_w<<<768,  256, 0, stream>>>(cw1, WC1, 128, 1536, 0, 128);
  build_hx<<<dim3(32, 4, 64), 256, 0, stream>>>(h0, BB(0), BB(1), BB(2));      // A,B + x0T->C
  build_hx<<<dim3(32, 4, 64), 256, 0, stream>>>(h1, OH1a, OH1b, BB(3));        // h1T->D

  // x-part exact chains + additive preacts
  xch0_build<<<512, 256, 0, stream>>>(inputs, XC(0));
  xch_diffuse<<<1024, 128, 0, stream>>>(S0b, XC(0), XC(1));
  xch_cheb   <<<1024, 128, 0, stream>>>(S0b, XC(1), XC(0), XC(2));
  xch_diffuse<<<1024, 128, 0, stream>>>(S1b, XC(0), XC(3));
  xch_cheb   <<<1024, 128, 0, stream>>>(S1b, XC(3), XC(0), XC(4));
  xg_build<<<65536, 256, 0, stream>>>(gw0, cw0, XCH, XGg, XGc);

  DiffJobs dj{};
  // L0 s-chain: {s1: S0*x0T -> H(+T I) ; s3: S1*x0T -> J(+T K)}
  dj.j[0] = {BB(2), S0b, BB(7), BB(8)};
  dj.j[1] = {BB(2), S1b, BB(9), BB(10)};
  gemm_diffz<<<dim3(64, 8, 2), 256, 0, stream>>>(dj);
  // {s2: S0*s1T -> L ; s4: S1*s3T -> M}
  dj.j[0] = {BB(8),  S0b, BB(11), nullptr};
  dj.j[1] = {BB(10), S1b, BB(12), nullptr};
  gemm_diffz<<<dim3(64, 8, 2), 256, 0, stream>>>(dj);

  // GATE0: segs {A,B,H,L,J,M}; rhN->C, rhlo->K, rhT->I
  Segs sg0{};
  sg0.p[0] = BB(0); sg0.p[1] = BB(1); sg0.p[2] = BB(7); sg0.p[3] = BB(11); sg0.p[4] = BB(9); sg0.p[5] = BB(12);
  gemm_wseg<0><<<dim3(2, 512), 256, 0, stream>>>(sg0, WG0, 768, gb0, h0, XGg,
      BB(2), BB(10), BB(8), USIG, nullptr, nullptr, nullptr, nullptr);

  // L0 c-chain: {c1: S0*rhT -> E(+T F) ; c3: S1*rhT -> A(+T B)}
  dj.j[0] = {BB(8), S0b, BB(4), BB(5)};
  dj.j[1] = {BB(8), S1b, BB(0), BB(1)};
  gemm_diffz<<<dim3(64, 8, 2), 256, 0, stream>>>(dj);
  // {c2: S0*c1T -> H ; c4: S1*c3T -> J}
  dj.j[0] = {BB(5), S0b, BB(7), nullptr};
  dj.j[1] = {BB(1), S1b, BB(9), nullptr};
  gemm_diffz<<<dim3(64, 8, 2), 256, 0, stream>>>(dj);

  // CAND0: segs {C,K,E,H,A,J}; xadd=XGc; out_h0; xaN->L, xalo->M, xaT->B
  Segs sc0{};
  sc0.p[0] = BB(2); sc0.p[1] = BB(10); sc0.p[2] = BB(4); sc0.p[3] = BB(7); sc0.p[4] = BB(0); sc0.p[5] = BB(9);
  gemm_wseg<1><<<dim3(1, 512), 256, 0, stream>>>(sc0, WC0, 768, cb0, h0, XGc,
      nullptr, nullptr, nullptr, USIG, out_h0, BB(11), BB(12), BB(1));

  // L1 wave-1 (z=4)
  dj.j[0] = {BB(1), S0b, BB(0), BB(2)};
  dj.j[1] = {BB(1), S1b, BB(4), BB(5)};
  dj.j[2] = {BB(3), S0b, BB(8), BB(6)};
  dj.j[3] = {BB(3), S1b, BB(9), BB(7)};
  gemm_diffz<<<dim3(64, 8, 4), 256, 0, stream>>>(dj);
  dj.j[0] = {BB(2), S0b, BB(10), nullptr};
  dj.j[1] = {BB(5), S1b, BB(3),  nullptr};
  gemm_diffz<<<dim3(64, 8, 2), 256, 0, stream>>>(dj);
  dj.j[0] = {BB(6), S0b, BB(1), nullptr};
  dj.j[1] = {BB(7), S1b, BB(2), nullptr};
  gemm_diffz<<<dim3(64, 8, 2), 256, 0, stream>>>(dj);

  // GATE1: segs x{L,M,A,K,E,D} h{OH1a,OH1b,I,B,J,C}; rh1N->F, rh1lo->H, rh1T->G
  Segs sg1{};
  sg1.p[0] = BB(11); sg1.p[1] = BB(12); sg1.p[2] = BB(0); sg1.p[3] = BB(10); sg1.p[4] = BB(4); sg1.p[5] = BB(3);
  sg1.p[6] = OH1a;   sg1.p[7] = OH1b;   sg1.p[8] = BB(8); sg1.p[9] = BB(1);  sg1.p[10] = BB(9); sg1.p[11] = BB(2);
  gemm_wseg<0><<<dim3(2, 512), 256, 0, stream>>>(sg1, WG1, 1536, gb1, h1, nullptr,
      BB(5), BB(7), BB(6), USIG, nullptr, nullptr, nullptr, nullptr);

  // L1 d-chain
  dj.j[0] = {BB(6), S0b, BB(8), BB(1)};
  dj.j[1] = {BB(6), S1b, BB(9), BB(2)};
  gemm_diffz<<<dim3(64, 8, 2), 256, 0, stream>>>(dj);
  dj.j[0] = {BB(1), S0b, BB(6), nullptr};
  gemm_diffz<<<dim3(64, 8, 1), 256, 0, stream>>>(dj);
  dj.j[0] = {BB(2), S1b, BB(1), nullptr};
  gemm_diffz<<<dim3(64, 8, 1), 256, 0, stream>>>(dj);

  // CAND1
  Segs sc1{};
  sc1.p[0] = BB(11); sc1.p[1] = BB(12); sc1.p[2] = BB(0); sc1.p[3] = BB(10); sc1.p[4] = BB(4); sc1.p[5] = BB(3);
  sc1.p[6] = BB(5);  sc1.p[7] = BB(7);  sc1.p[8] = BB(8); sc1.p[9] = BB(6);  sc1.p[10] = BB(9); sc1.p[11] = BB(1);
  gemm_wseg<1><<<dim3(1, 512), 256, 0, stream>>>(sc1, WC1, 1536, cb1, h1, nullptr,
      nullptr, nullptr, nullptr, USIG, out_h1, nullptr, nullptr, nullptr);

  // projection
  proj_k<<<16384, 256, 0, stream>>>(out_h1, pw, pb, out);
}

// Round 9
// 1110.455 us; speedup vs baseline: 1.6220x; 1.0512x over previous
//
#include <hip/hip_runtime.h>
#include <hip/hip_bf16.h>

typedef unsigned short u16;
typedef unsigned int u32;
typedef __attribute__((ext_vector_type(2))) unsigned int u32x2;
typedef __attribute__((ext_vector_type(4))) float f32x4;
typedef __attribute__((ext_vector_type(8))) __bf16 bf16x8;

#define DEVI static __device__ __forceinline__

// ---------- scalar helpers ----------
DEVI u16 f2bf(float x) {
  union { float f; u32 u; } v; v.f = x;
  u32 r = v.u + 0x7fffu + ((v.u >> 16) & 1u);
  return (u16)(r >> 16);
}
DEVI float bf2f(u16 h) { union { u32 u; float f; } v; v.u = ((u32)h) << 16; return v.f; }
DEVI u32 pk2bf(float a, float b) { return (u32)f2bf(a) | ((u32)f2bf(b) << 16); }
DEVI float sigm(float x) { return 1.f / (1.f + __expf(-x)); }
DEVI float tanh_(float x) {
  float a = fabsf(x);
  float e = __expf(-2.f * a);
  float t = (1.f - e) / (1.f + e);
  return copysignf(t, x);
}

DEVI void gl_lds16(const u16* g, void* l) {
  __builtin_amdgcn_global_load_lds(
      (const __attribute__((address_space(1))) u32*)(const void*)g,
      (__attribute__((address_space(3))) u32*)l, 16, 0, 0);
}
DEVI f32x4 mfma16(bf16x8 a, bf16x8 b, f32x4 c) {
  return __builtin_amdgcn_mfma_f32_16x16x32_bf16(a, b, c, 0, 0, 0);
}

// 64B-row LDS swizzle key (R8-proven: zero conflicts).
#define SWZ(row) (((row) >> 1) & 3)

// ---------- prep kernels ----------
__global__ void sums_k(const float* __restrict__ adj, float* __restrict__ rs, float* __restrict__ cs) {
  __shared__ float red[256];
  int bid = blockIdx.x, tid = threadIdx.x;
  if (bid < 1024) {
    float a = 0.f;
    for (int j = tid; j < 1024; j += 256) a += adj[bid * 1024 + j];
    red[tid] = a; __syncthreads();
    for (int s = 128; s; s >>= 1) { if (tid < s) red[tid] += red[tid + s]; __syncthreads(); }
    if (!tid) rs[bid] = red[0];
  } else {
    int c0 = (bid - 1024) * 64;
    int c = tid & 63, r0 = tid >> 6;
    float a = 0.f;
    for (int r = r0; r < 1024; r += 4) a += adj[r * 1024 + c0 + c];
    red[tid] = a; __syncthreads();
    if (tid < 64) cs[c0 + c] = red[c] + red[64 + c] + red[128 + c] + red[192 + c];
  }
}

__global__ void s0_build(const float* __restrict__ adj, const float* __restrict__ rs, u16* __restrict__ S0) {
  __shared__ float tile[32][33];
  int i0 = blockIdx.x * 32, j0 = blockIdx.y * 32;
  int tx = threadIdx.x & 31, ty = threadIdx.x >> 5;
  for (int yy = ty; yy < 32; yy += 8)
    tile[yy][tx] = adj[(j0 + yy) * 1024 + i0 + tx];
  __syncthreads();
  for (int yy = ty; yy < 32; yy += 8)
    S0[(i0 + yy) * 1024 + j0 + tx] = f2bf(tile[tx][yy] / rs[j0 + tx]);
}

__global__ void s1_build(const float* __restrict__ adj, const float* __restrict__ cs, u16* __restrict__ S1) {
  int idx = blockIdx.x * 256 + threadIdx.x;
  int j = idx & 1023;
  S1[idx] = f2bf(adj[idx] / cs[j]);
}

__global__ void pack_w(const float* __restrict__ src, u16* __restrict__ dst,
                       int NO, int Ktot, int off0, int off1) {
  int idx = blockIdx.x * 256 + threadIdx.x;
  if (idx >= NO * Ktot) return;
  int o = idx / Ktot, k = idx % Ktot;
  int seg = k >> 7, i = k & 127;
  int mo = seg % 6;
  int pos = ((seg / 6) ? off1 : off0) + i;
  const float* wr = src + (long)pos * 5 * NO + o;
  float v;
  switch (mo) {
    case 0: case 1: v = wr[0] - wr[(long)2 * NO] - wr[(long)4 * NO]; break;
    case 2: v = wr[(long)1 * NO]; break;
    case 3: v = 2.f * wr[(long)2 * NO]; break;
    case 4: v = wr[(long)3 * NO]; break;
    default: v = 2.f * wr[(long)4 * NO]; break;
  }
  dst[idx] = f2bf(v);
}

__global__ void build_hx(const float* __restrict__ src, u16* __restrict__ hiN,
                         u16* __restrict__ loN, u16* __restrict__ hiT) {
  __shared__ u16 t[32][33];
  int n0 = blockIdx.x * 32, u0 = blockIdx.y * 32, b = blockIdx.z;
  int tx = threadIdx.x & 31, ty = threadIdx.x >> 5;
  for (int yy = ty; yy < 32; yy += 8) {
    long d = (long)b * 131072 + (n0 + yy) * 128 + u0 + tx;
    float v = src[d];
    u16 h = f2bf(v);
    hiN[d] = h;
    loN[d] = f2bf(v - bf2f(h));
    t[yy][tx] = h;
  }
  __syncthreads();
  for (int yy = ty; yy < 32; yy += 8)
    hiT[(long)(b * 128 + u0 + yy) * 1024 + n0 + tx] = t[tx][yy];
}

// ---------- x-part (layer 0): exact fp32 path ----------
__global__ void xch0_build(const float* __restrict__ inp, float* __restrict__ x0) {
  int idx = blockIdx.x * 256 + threadIdx.x;
  int n = idx >> 7, c = idx & 127, b = c >> 1, d = c & 1;
  x0[idx] = inp[b * 2048 + n * 2 + d];
}

__global__ void xch_diffuse(const u16* __restrict__ S, const float* __restrict__ xin,
                            float* __restrict__ xout) {
  int n = blockIdx.x, c = threadIdx.x;
  float acc = 0.f;
  for (int k = 0; k < 1024; k++) acc += bf2f(S[n * 1024 + k]) * xin[k * 128 + c];
  xout[n * 128 + c] = acc;
}

__global__ void xch_cheb(const u16* __restrict__ S, const float* __restrict__ xin,
                         const float* __restrict__ x0, float* __restrict__ xout) {
  int n = blockIdx.x, c = threadIdx.x;
  float acc = 0.f;
  for (int k = 0; k < 1024; k++) acc += bf2f(S[n * 1024 + k]) * xin[k * 128 + c];
  xout[n * 128 + c] = 2.f * acc - x0[n * 128 + c];
}

__global__ void xg_build(const float* __restrict__ gw0, const float* __restrict__ cw0,
                         const float* __restrict__ xch,
                         u16* __restrict__ xgg, u16* __restrict__ xgc) {
  int r = blockIdx.x;
  int n = r & 1023, b = r >> 10;
  int t = threadIdx.x;
  __shared__ float xv[10];
  if (t < 10) { int m = t % 5, p = t / 5; xv[t] = xch[(long)m * 131072 + n * 128 + b * 2 + p]; }
  __syncthreads();
  float a = 0.f;
#pragma unroll
  for (int q = 0; q < 10; q++) { int m = q % 5, p = q / 5;
    a += gw0[(long)(p * 5 + m) * 256 + t] * xv[q]; }
  xgg[(long)r * 256 + t] = f2bf(a);
  if (t < 128) {
    float a2 = 0.f;
#pragma unroll
    for (int q = 0; q < 10; q++) { int m = q % 5, p = q / 5;
      a2 += cw0[(long)(p * 5 + m) * 128 + t] * xv[q]; }
    xgc[(long)r * 128 + t] = f2bf(a2);
  }
}

// ---------- fused diffusion GEMM (256x256 tile, 8 waves, triple-buffered) ----------
struct DiffJob { const u16* X; const u16* S; u16* YN; u16* YT; };
struct DiffJobs { DiffJob j[4]; };

__global__ __launch_bounds__(512, 2) void gemm_diffz(DiffJobs jobs) {
  DiffJob J = jobs.j[blockIdx.z];
  constexpr int BUF = 512 * 64;                 // 256 S-rows + 256 X-rows, 64B each
  __shared__ char smem[3 * BUF];
  const int tid = threadIdx.x, wid = tid >> 6, lane = tid & 63;
  const int wrM = wid >> 2, wcN = wid & 3, l15 = lane & 15, l4 = lane >> 4;
  const int s_row = lane >> 2, s_kcp = lane & 3;
  const int ntile = blockIdx.y * 256;
  const int fbase = blockIdx.x * 256;

  f32x4 acc[8][4];
#pragma unroll
  for (int i = 0; i < 8; i++)
#pragma unroll
    for (int j = 0; j < 4; j++) acc[i][j] = (f32x4){0.f, 0.f, 0.f, 0.f};

  auto stage = [&](char* buf, int ks) {
    const int k0 = ks * 32;
#pragma unroll
    for (int c = 0; c < 4; c++) {
      const int row0 = c * 128 + wid * 16;      // wave-uniform
      const int row = row0 + s_row;             // per-lane (source only)
      const u16* src;
      if (row0 < 256) src = J.S + (long)(ntile + row) * 1024 + k0 + ((s_kcp ^ SWZ(row)) * 8);
      else { const int fr = row - 256; src = J.X + (long)(fbase + fr) * 1024 + k0 + ((s_kcp ^ SWZ(fr)) * 8); }
      gl_lds16(src, buf + row0 * 64);
    }
  };
  auto compute = [&](char* buf) {
    char* Ab = buf; char* Bb = buf + 256 * 64;
    bf16x8 af[8], bfr[4];
#pragma unroll
    for (int mb = 0; mb < 8; mb++) {
      const int row = wrM * 128 + mb * 16 + l15;
      af[mb] = *(const bf16x8*)(Ab + row * 64 + ((l4 ^ SWZ(row)) * 16));
    }
#pragma unroll
    for (int nb = 0; nb < 4; nb++) {
      const int row = wcN * 64 + nb * 16 + l15;
      bfr[nb] = *(const bf16x8*)(Bb + row * 64 + ((l4 ^ SWZ(row)) * 16));
    }
#pragma unroll
    for (int mb = 0; mb < 8; mb++)
#pragma unroll
      for (int nb = 0; nb < 4; nb++)
        acc[mb][nb] = mfma16(af[mb], bfr[nb], acc[mb][nb]);
  };

  const int NKS = 32;
  stage(smem, 0);
  stage(smem + BUF, 1);
  char* cur = smem; char* mid = smem + BUF; char* fut = smem + 2 * BUF;
  for (int ks = 0; ks + 2 < NKS; ks++) {
    stage(fut, ks + 2);
    asm volatile("s_waitcnt vmcnt(8)" ::: "memory");
    __builtin_amdgcn_s_barrier();
    __builtin_amdgcn_sched_barrier(0);
    compute(cur);
    asm volatile("" ::: "memory");
    __builtin_amdgcn_s_barrier();
    __builtin_amdgcn_sched_barrier(0);
    char* t = cur; cur = mid; mid = fut; fut = t;
  }
  asm volatile("s_waitcnt vmcnt(4)" ::: "memory");
  __builtin_amdgcn_s_barrier();
  __builtin_amdgcn_sched_barrier(0);
  compute(cur);
  asm volatile("s_waitcnt vmcnt(0)" ::: "memory");
  __builtin_amdgcn_s_barrier();
  __builtin_amdgcn_sched_barrier(0);
  compute(mid);

#pragma unroll
  for (int mb = 0; mb < 8; mb++) {
#pragma unroll
    for (int nb = 0; nb < 4; nb++) {
      const int n0 = ntile + wrM * 128 + mb * 16 + l4 * 4;
      const int f  = fbase + wcN * 64 + nb * 16 + l15;
      const int b = f >> 7, u = f & 127;
      f32x4 v = acc[mb][nb];
      u16 h0 = f2bf(v[0]), h1 = f2bf(v[1]), h2 = f2bf(v[2]), h3 = f2bf(v[3]);
      u16* yn = J.YN + (long)b * 131072 + (long)n0 * 128 + u;
      yn[0] = h0; yn[128] = h1; yn[256] = h2; yn[384] = h3;
      if (J.YT != nullptr) {
        u32x2 wv; wv[0] = (u32)h0 | ((u32)h1 << 16); wv[1] = (u32)h2 | ((u32)h3 << 16);
        *(u32x2*)(J.YT + (long)f * 1024 + n0) = wv;
      }
    }
  }
}

// ---------- W GEMM with fused epilogue (256-wide N tile, 8 waves) ----------
struct Segs { const u16* p[12]; };
DEVI const u16* seg_sel(const Segs& s, int i) {
  switch (i) {
    case 0: return s.p[0]; case 1: return s.p[1]; case 2: return s.p[2];
    case 3: return s.p[3]; case 4: return s.p[4]; case 5: return s.p[5];
    case 6: return s.p[6]; case 7: return s.p[7]; case 8: return s.p[8];
    case 9: return s.p[9]; case 10: return s.p[10]; default: return s.p[11];
  }
}

template<int EPI>   // 0 = GATE (M=256), 1 = CAND (M=128)
__global__ __launch_bounds__(512, 2) void gemm_wseg(
    Segs segs, const u16* __restrict__ WT, int Ktot,
    const float* __restrict__ bias, const float* __restrict__ Hprev,
    const u16* __restrict__ xadd,
    u16* __restrict__ rh_hi, u16* __restrict__ rh_lo, u16* __restrict__ rh_t,
    u16* __restrict__ usig,
    float* __restrict__ hnew_out, u16* __restrict__ xa_hi, u16* __restrict__ xa_lo,
    u16* __restrict__ xa_t)
{
  constexpr int TM = (EPI == 0) ? 256 : 128;
  constexpr int MB = (EPI == 0) ? 8 : 4;
  constexpr int MW = (EPI == 0) ? 128 : 64;
  constexpr int ROUNDS = (TM + 256) / 128;
  constexpr int BUF = (TM + 256) * 64;
  __shared__ char smem[3 * BUF];
  const int tid = threadIdx.x, wid = tid >> 6, lane = tid & 63;
  const int wrM = wid >> 2, wcN = wid & 3, l15 = lane & 15, l4 = lane >> 4;
  const int s_row = lane >> 2, s_kcp = lane & 3;
  const int rtile = blockIdx.x * 256;

  f32x4 acc[MB][4];
#pragma unroll
  for (int i = 0; i < MB; i++)
#pragma unroll
    for (int j = 0; j < 4; j++) acc[i][j] = (f32x4){0.f, 0.f, 0.f, 0.f};

  const int NKS = Ktot >> 5;
  auto stage = [&](char* buf, int ks) {
    const int k0 = ks * 32;
    const int sidx = ks >> 2, si0 = (ks & 3) * 32;
    const u16* sp = seg_sel(segs, sidx);
#pragma unroll
    for (int c = 0; c < ROUNDS; c++) {
      const int row0 = c * 128 + wid * 16;      // wave-uniform
      const int row = row0 + s_row;             // per-lane (source only)
      const u16* src;
      if (row0 < TM) src = WT + (long)row * Ktot + k0 + ((s_kcp ^ SWZ(row)) * 8);
      else { const int br = row - TM; src = sp + (long)(rtile + br) * 128 + si0 + ((s_kcp ^ SWZ(br)) * 8); }
      gl_lds16(src, buf + row0 * 64);
    }
  };
  auto compute = [&](char* buf) {
    char* Ab = buf; char* Bb = buf + TM * 64;
    bf16x8 af[MB], bfr[4];
#pragma unroll
    for (int mb = 0; mb < MB; mb++) {
      const int row = wrM * MW + mb * 16 + l15;
      af[mb] = *(const bf16x8*)(Ab + row * 64 + ((l4 ^ SWZ(row)) * 16));
    }
#pragma unroll
    for (int nb = 0; nb < 4; nb++) {
      const int row = wcN * 64 + nb * 16 + l15;
      bfr[nb] = *(const bf16x8*)(Bb + row * 64 + ((l4 ^ SWZ(row)) * 16));
    }
#pragma unroll
    for (int mb = 0; mb < MB; mb++)
#pragma unroll
      for (int nb = 0; nb < 4; nb++)
        acc[mb][nb] = mfma16(af[mb], bfr[nb], acc[mb][nb]);
  };

  stage(smem, 0);
  stage(smem + BUF, 1);
  char* cur = smem; char* mid = smem + BUF; char* fut = smem + 2 * BUF;
  for (int ks = 0; ks + 2 < NKS; ks++) {
    stage(fut, ks + 2);
    if constexpr (ROUNDS == 4) asm volatile("s_waitcnt vmcnt(8)" ::: "memory");
    else                       asm volatile("s_waitcnt vmcnt(6)" ::: "memory");
    __builtin_amdgcn_s_barrier();
    __builtin_amdgcn_sched_barrier(0);
    compute(cur);
    asm volatile("" ::: "memory");
    __builtin_amdgcn_s_barrier();
    __builtin_amdgcn_sched_barrier(0);
    char* t = cur; cur = mid; mid = fut; fut = t;
  }
  if constexpr (ROUNDS == 4) asm volatile("s_waitcnt vmcnt(4)" ::: "memory");
  else                       asm volatile("s_waitcnt vmcnt(3)" ::: "memory");
  __builtin_amdgcn_s_barrier();
  __builtin_amdgcn_sched_barrier(0);
  compute(cur);
  asm volatile("s_waitcnt vmcnt(0)" ::: "memory");
  __builtin_amdgcn_s_barrier();
  __builtin_amdgcn_sched_barrier(0);
  compute(mid);

#pragma unroll
  for (int mb = 0; mb < MB; mb++) {
#pragma unroll
    for (int nb = 0; nb < 4; nb++) {
      const int o = wrM * MW + mb * 16 + l4 * 4;
      const int rr = rtile + wcN * 64 + nb * 16 + l15;
      const int n = rr & 1023, b = rr >> 10;
      f32x4 v = acc[mb][nb];
      float4 bv = *(const float4*)(bias + o);
      float a0 = 0.f, a1 = 0.f, a2 = 0.f, a3 = 0.f;
      if (xadd != nullptr) {
        const int xs = (EPI == 0) ? 256 : 128;
        u32x2 xv = *(const u32x2*)(xadd + (long)rr * xs + o);
        a0 = bf2f((u16)(xv[0] & 0xffffu)); a1 = bf2f((u16)(xv[0] >> 16));
        a2 = bf2f((u16)(xv[1] & 0xffffu)); a3 = bf2f((u16)(xv[1] >> 16));
      }
      if (EPI == 0) {
        float s0 = sigm(v[0] + bv.x + a0), s1 = sigm(v[1] + bv.y + a1);
        float s2 = sigm(v[2] + bv.z + a2), s3 = sigm(v[3] + bv.w + a3);
        if (o < 128) {
          float4 hv = *(const float4*)(Hprev + (long)rr * 128 + o);
          float r0 = s0 * hv.x, r1 = s1 * hv.y, r2 = s2 * hv.z, r3 = s3 * hv.w;
          u16 h0 = f2bf(r0), h1 = f2bf(r1), h2 = f2bf(r2), h3 = f2bf(r3);
          long d = (long)rr * 128 + o;
          u32x2 wh; wh[0] = (u32)h0 | ((u32)h1 << 16); wh[1] = (u32)h2 | ((u32)h3 << 16);
          *(u32x2*)(rh_hi + d) = wh;
          u32x2 wl; wl[0] = pk2bf(r0 - bf2f(h0), r1 - bf2f(h1));
          wl[1] = pk2bf(r2 - bf2f(h2), r3 - bf2f(h3));
          *(u32x2*)(rh_lo + d) = wl;
          u16* rt = rh_t + (long)(b * 128 + o) * 1024 + n;
          rt[0] = h0; rt[1024] = h1; rt[2048] = h2; rt[3072] = h3;
        } else {
          u32x2 wu; wu[0] = pk2bf(s0, s1); wu[1] = pk2bf(s2, s3);
          *(u32x2*)(usig + (long)rr * 128 + (o - 128)) = wu;
        }
      } else {
        float c0 = tanh_(v[0] + bv.x + a0), c1 = tanh_(v[1] + bv.y + a1);
        float c2 = tanh_(v[2] + bv.z + a2), c3 = tanh_(v[3] + bv.w + a3);
        u32x2 uv = *(const u32x2*)(usig + (long)rr * 128 + o);
        float u0 = bf2f((u16)(uv[0] & 0xffffu)), u1 = bf2f((u16)(uv[0] >> 16));
        float u2 = bf2f((u16)(uv[1] & 0xffffu)), u3 = bf2f((u16)(uv[1] >> 16));
        float4 hv = *(const float4*)(Hprev + (long)rr * 128 + o);
        float h0n = u0 * hv.x + (1.f - u0) * c0;
        float h1n = u1 * hv.y + (1.f - u1) * c1;
        float h2n = u2 * hv.z + (1.f - u2) * c2;
        float h3n = u3 * hv.w + (1.f - u3) * c3;
        *(float4*)(hnew_out + (long)rr * 128 + o) = make_float4(h0n, h1n, h2n, h3n);
        if (xa_hi != nullptr) {
          u16 x0 = f2bf(h0n), x1 = f2bf(h1n), x2 = f2bf(h2n), x3 = f2bf(h3n);
          long d = (long)rr * 128 + o;
          u32x2 wh; wh[0] = (u32)x0 | ((u32)x1 << 16); wh[1] = (u32)x2 | ((u32)x3 << 16);
          *(u32x2*)(xa_hi + d) = wh;
          u32x2 wl; wl[0] = pk2bf(h0n - bf2f(x0), h1n - bf2f(x1));
          wl[1] = pk2bf(h2n - bf2f(x2), h3n - bf2f(x3));
          *(u32x2*)(xa_lo + d) = wl;
          u16* xt = xa_t + (long)(b * 128 + o) * 1024 + n;
          xt[0] = x0; xt[1024] = x1; xt[2048] = x2; xt[3072] = x3;
        }
      }
    }
  }
}

// ---------- projection ----------
__global__ __launch_bounds__(256) void proj_k(const float* __restrict__ h1n, const float* __restrict__ pw,
                                              const float* __restrict__ pb, float* __restrict__ out) {
  int wid = threadIdx.x >> 6, lane = threadIdx.x & 63;
  int r = blockIdx.x * 4 + wid;
  int b = r >> 10, n = r & 1023;
  const float* hp = h1n + (long)b * 131072 + n * 128;
  float ha = hp[lane], hb = hp[lane + 64];
  float p0 = ha * pw[lane * 2]     + hb * pw[(lane + 64) * 2];
  float p1 = ha * pw[lane * 2 + 1] + hb * pw[(lane + 64) * 2 + 1];
  for (int off = 32; off; off >>= 1) { p0 += __shfl_down(p0, off); p1 += __shfl_down(p1, off); }
  if (!lane) {
    out[(long)b * 2048 + n * 2]     = p0 + pb[0];
    out[(long)b * 2048 + n * 2 + 1] = p1 + pb[1];
  }
}

// ---------- host ----------
extern "C" void kernel_launch(void* const* d_in, const int* in_sizes, int n_in,
                              void* d_out, int out_size, void* d_ws, size_t ws_size,
                              hipStream_t stream) {
  (void)in_sizes; (void)n_in; (void)out_size; (void)ws_size;
  const float* inputs = (const float*)d_in[0];
  const float* hidden = (const float*)d_in[1];
  const float* adj    = (const float*)d_in[2];
  const float* gw0 = (const float*)d_in[3];
  const float* gb0 = (const float*)d_in[4];
  const float* cw0 = (const float*)d_in[5];
  const float* cb0 = (const float*)d_in[6];
  const float* gw1 = (const float*)d_in[7];
  const float* gb1 = (const float*)d_in[8];
  const float* cw1 = (const float*)d_in[9];
  const float* cb1 = (const float*)d_in[10];
  const float* pw  = (const float*)d_in[11];
  const float* pb  = (const float*)d_in[12];

  float* out    = (float*)d_out;
  float* out_h0 = out + 131072;
  float* out_h1 = out_h0 + 8388608;
  const float* h0 = hidden;
  const float* h1 = hidden + 8388608;

  u16* OH1a = (u16*)out_h1;            // h1 hiN
  u16* OH1b = OH1a + 8388608;          // h1 loN

  char* wp = (char*)d_ws;
  auto alloc = [&](size_t bytes) { char* r = wp; wp += (bytes + 255) & ~(size_t)255; return r; };
  u16*   S0b  = (u16*)  alloc(1048576 * 2);
  u16*   S1b  = (u16*)  alloc(1048576 * 2);
  float* rs   = (float*)alloc(1024 * 4);
  float* cs   = (float*)alloc(1024 * 4);
  u16*   WG0  = (u16*)  alloc((size_t)256 * 768 * 2);
  u16*   WC0  = (u16*)  alloc((size_t)128 * 768 * 2);
  u16*   WG1  = (u16*)  alloc((size_t)256 * 1536 * 2);
  u16*   WC1  = (u16*)  alloc((size_t)128 * 1536 * 2);
  u16*   Bb   = (u16*)  alloc((size_t)13 * 8388608 * 2);   // 13 chain slots
  u16*   USIG = (u16*)  alloc((size_t)8388608 * 2);
  float* XCH  = (float*)alloc((size_t)5 * 131072 * 4);
  auto BB = [&](int i) { return Bb + (size_t)i * 8388608; };
  auto XC = [&](int i) { return XCH + (size_t)i * 131072; };
  u16* XGg = BB(4);   // spans slots 4,5
  u16* XGc = BB(6);

  // prep
  sums_k<<<1040, 256, 0, stream>>>(adj, rs, cs);
  s0_build<<<dim3(32, 32), 256, 0, stream>>>(adj, rs, S0b);
  s1_build<<<4096, 256, 0, stream>>>(adj, cs, S1b);
  pack_w<<<768,  256, 0, stream>>>(gw0, WG0, 256, 768, 2, 0);
  pack_w<<<384,  256, 0, stream>>>(cw0, WC0, 128, 768, 2, 0);
  pack_w<<<1536, 256, 0, stream>>>(gw1, WG1, 256, 1536, 0, 128);
  pack_w<<<768,  256, 0, stream>>>(cw1, WC1, 128, 1536, 0, 128);
  build_hx<<<dim3(32, 4, 64), 256, 0, stream>>>(h0, BB(0), BB(1), BB(2));      // A,B + x0T->C
  build_hx<<<dim3(32, 4, 64), 256, 0, stream>>>(h1, OH1a, OH1b, BB(3));        // h1T->D

  // x-part exact chains + additive preacts
  xch0_build<<<512, 256, 0, stream>>>(inputs, XC(0));
  xch_diffuse<<<1024, 128, 0, stream>>>(S0b, XC(0), XC(1));
  xch_cheb   <<<1024, 128, 0, stream>>>(S0b, XC(1), XC(0), XC(2));
  xch_diffuse<<<1024, 128, 0, stream>>>(S1b, XC(0), XC(3));
  xch_cheb   <<<1024, 128, 0, stream>>>(S1b, XC(3), XC(0), XC(4));
  xg_build<<<65536, 256, 0, stream>>>(gw0, cw0, XCH, XGg, XGc);

  DiffJobs dj{};
  // L0 s-chain: {s1: S0*x0T -> H(+T I) ; s3: S1*x0T -> J(+T K)}
  dj.j[0] = {BB(2), S0b, BB(7), BB(8)};
  dj.j[1] = {BB(2), S1b, BB(9), BB(10)};
  gemm_diffz<<<dim3(32, 4, 2), 512, 0, stream>>>(dj);
  // {s2: S0*s1T -> L ; s4: S1*s3T -> M}
  dj.j[0] = {BB(8),  S0b, BB(11), nullptr};
  dj.j[1] = {BB(10), S1b, BB(12), nullptr};
  gemm_diffz<<<dim3(32, 4, 2), 512, 0, stream>>>(dj);

  // GATE0: segs {A,B,H,L,J,M}; rhN->C, rhlo->K, rhT->I
  Segs sg0{};
  sg0.p[0] = BB(0); sg0.p[1] = BB(1); sg0.p[2] = BB(7); sg0.p[3] = BB(11); sg0.p[4] = BB(9); sg0.p[5] = BB(12);
  gemm_wseg<0><<<256, 512, 0, stream>>>(sg0, WG0, 768, gb0, h0, XGg,
      BB(2), BB(10), BB(8), USIG, nullptr, nullptr, nullptr, nullptr);

  // L0 c-chain: {c1: S0*rhT -> E(+T F) ; c3: S1*rhT -> A(+T B)}
  dj.j[0] = {BB(8), S0b, BB(4), BB(5)};
  dj.j[1] = {BB(8), S1b, BB(0), BB(1)};
  gemm_diffz<<<dim3(32, 4, 2), 512, 0, stream>>>(dj);
  // {c2: S0*c1T -> H ; c4: S1*c3T -> J}
  dj.j[0] = {BB(5), S0b, BB(7), nullptr};
  dj.j[1] = {BB(1), S1b, BB(9), nullptr};
  gemm_diffz<<<dim3(32, 4, 2), 512, 0, stream>>>(dj);

  // CAND0: segs {C,K,E,H,A,J}; xadd=XGc; out_h0; xaN->L, xalo->M, xaT->B
  Segs sc0{};
  sc0.p[0] = BB(2); sc0.p[1] = BB(10); sc0.p[2] = BB(4); sc0.p[3] = BB(7); sc0.p[4] = BB(0); sc0.p[5] = BB(9);
  gemm_wseg<1><<<256, 512, 0, stream>>>(sc0, WC0, 768, cb0, h0, XGc,
      nullptr, nullptr, nullptr, USIG, out_h0, BB(11), BB(12), BB(1));

  // L1 wave-1 (z=4)
  dj.j[0] = {BB(1), S0b, BB(0), BB(2)};
  dj.j[1] = {BB(1), S1b, BB(4), BB(5)};
  dj.j[2] = {BB(3), S0b, BB(8), BB(6)};
  dj.j[3] = {BB(3), S1b, BB(9), BB(7)};
  gemm_diffz<<<dim3(32, 4, 4), 512, 0, stream>>>(dj);
  dj.j[0] = {BB(2), S0b, BB(10), nullptr};
  dj.j[1] = {BB(5), S1b, BB(3),  nullptr};
  gemm_diffz<<<dim3(32, 4, 2), 512, 0, stream>>>(dj);
  dj.j[0] = {BB(6), S0b, BB(1), nullptr};
  dj.j[1] = {BB(7), S1b, BB(2), nullptr};
  gemm_diffz<<<dim3(32, 4, 2), 512, 0, stream>>>(dj);

  // GATE1: segs x{L,M,A,K,E,D} h{OH1a,OH1b,I,B,J,C}; rh1N->F, rh1lo->H, rh1T->G
  Segs sg1{};
  sg1.p[0] = BB(11); sg1.p[1] = BB(12); sg1.p[2] = BB(0); sg1.p[3] = BB(10); sg1.p[4] = BB(4); sg1.p[5] = BB(3);
  sg1.p[6] = OH1a;   sg1.p[7] = OH1b;   sg1.p[8] = BB(8); sg1.p[9] = BB(1);  sg1.p[10] = BB(9); sg1.p[11] = BB(2);
  gemm_wseg<0><<<256, 512, 0, stream>>>(sg1, WG1, 1536, gb1, h1, nullptr,
      BB(5), BB(7), BB(6), USIG, nullptr, nullptr, nullptr, nullptr);

  // L1 d-chain
  dj.j[0] = {BB(6), S0b, BB(8), BB(1)};
  dj.j[1] = {BB(6), S1b, BB(9), BB(2)};
  gemm_diffz<<<dim3(32, 4, 2), 512, 0, stream>>>(dj);
  dj.j[0] = {BB(1), S0b, BB(6), nullptr};
  gemm_diffz<<<dim3(32, 4, 1), 512, 0, stream>>>(dj);
  dj.j[0] = {BB(2), S1b, BB(1), nullptr};
  gemm_diffz<<<dim3(32, 4, 1), 512, 0, stream>>>(dj);

  // CAND1
  Segs sc1{};
  sc1.p[0] = BB(11); sc1.p[1] = BB(12); sc1.p[2] = BB(0); sc1.p[3] = BB(10); sc1.p[4] = BB(4); sc1.p[5] = BB(3);
  sc1.p[6] = BB(5);  sc1.p[7] = BB(7);  sc1.p[8] = BB(8); sc1.p[9] = BB(6);  sc1.p[10] = BB(9); sc1.p[11] = BB(1);
  gemm_wseg<1><<<256, 512, 0, stream>>>(sc1, WC1, 1536, cb1, h1, nullptr,
      nullptr, nullptr, nullptr, USIG, out_h1, nullptr, nullptr, nullptr);

  // projection
  proj_k<<<16384, 256, 0, stream>>>(out_h1, pw, pb, out);
}